// Round 10
// baseline (255.128 us; speedup 1.0000x reference)
//
#include <hip/hip_runtime.h>

#define BATCH   2
#define SEQLEN  2048
#define DMODEL  1024
#define DINNER  2048
#define NHEADS  64
#define HEADDIM 32
#define DSTATE  16
#define CONVDIM 2080
#define DINPROJ 4192
#define NPAD    4224
#define CHUNK   256
#define NCHUNK  8
#define BL      (BATCH*SEQLEN)   // 4096
#define XWIDTH  2144             // CONVDIM + NHEADS
#define XW4     (XWIDTH/4)       // 536

typedef float          f4    __attribute__((ext_vector_type(4)));
typedef short          s16x8 __attribute__((ext_vector_type(8)));
typedef unsigned short u16x4 __attribute__((ext_vector_type(4)));
typedef __bf16         bf16x8 __attribute__((ext_vector_type(8)));
typedef float          f32x4v __attribute__((ext_vector_type(4)));

#define MFMA16(a,b,c) __builtin_amdgcn_mfma_f32_16x16x32_bf16((a),(b),(c),0,0,0)

__device__ __forceinline__ unsigned short f2bf(float f){
  unsigned int u = __float_as_uint(f);
  u += 0x7FFFu + ((u >> 16) & 1u);
  return (unsigned short)(u >> 16);
}
__device__ __forceinline__ float bf2f(unsigned short u){
  return __uint_as_float(((unsigned int)u) << 16);
}

__device__ __forceinline__ void gload_lds16(const void* g, void* l){
  __builtin_amdgcn_global_load_lds((const __attribute__((address_space(1))) unsigned int*)g,
                                   (__attribute__((address_space(3))) unsigned int*)l,
                                   16, 0, 0);
}

__device__ __forceinline__ bf16x8 f32x8_to_frag(const float* src, bool valid){
  bf16x8 r;
  if (valid) {
    f4 a = *(const f4*)src;
    f4 c = *(const f4*)(src + 4);
    r[0]=(__bf16)a[0]; r[1]=(__bf16)a[1]; r[2]=(__bf16)a[2]; r[3]=(__bf16)a[3];
    r[4]=(__bf16)c[0]; r[5]=(__bf16)c[1]; r[6]=(__bf16)c[2]; r[7]=(__bf16)c[3];
  } else {
    r[0]=(__bf16)0.f; r[1]=(__bf16)0.f; r[2]=(__bf16)0.f; r[3]=(__bf16)0.f;
    r[4]=(__bf16)0.f; r[5]=(__bf16)0.f; r[6]=(__bf16)0.f; r[7]=(__bf16)0.f;
  }
  return r;
}

__device__ __forceinline__ bf16x8 bf16x8_load(const unsigned short* src, bool valid){
  if (valid) {
    s16x8 v = *(const s16x8*)src;
    return *(bf16x8*)&v;
  }
  bf16x8 r;
  r[0]=(__bf16)0.f; r[1]=(__bf16)0.f; r[2]=(__bf16)0.f; r[3]=(__bf16)0.f;
  r[4]=(__bf16)0.f; r[5]=(__bf16)0.f; r[6]=(__bf16)0.f; r[7]=(__bf16)0.f;
  return r;
}

// ---------------- casts ----------------
__global__ void cast_f32_bf16(const float* __restrict__ in, unsigned short* __restrict__ out, int n){
  int i = blockIdx.x * 256 + threadIdx.x;
  if (i < n) out[i] = f2bf(in[i]);
}

__global__ void cast_win_pad(const float* __restrict__ in, unsigned short* __restrict__ out){
  int i = blockIdx.x * 256 + threadIdx.x;
  if (i >= NPAD * DMODEL) return;
  int r = i >> 10;  // /1024
  out[i] = (r < DINPROJ) ? f2bf(in[i]) : (unsigned short)0;
}

// ======= in_proj GEMM 256x128: minimizes staged bytes (396 MB vs 540 for 128^2) =======
// C[M,N] = A[M,K]*B[N,K]^T, K=1024. 256 thr = 4 waves (2M x 2N), wave-tile 128x64,
// acc[8][4] = 32 MFMA/iter/wave. LDS 48KB -> 3 blocks/CU. Counted-vmcnt 2-deep
// pipeline (6 loads/stage -> vmcnt(6)); conflict-free chunk-XOR swizzle (R5-verified).
__global__ __launch_bounds__(256) void gemm_in_256128(
    const unsigned short* __restrict__ A,   // [4096][1024]
    const unsigned short* __restrict__ B,   // [4224][1024]
    float* __restrict__ C0, float* __restrict__ C1)
{
  __shared__ unsigned short As[2][256][32];
  __shared__ unsigned short Bs[2][128][32];
  const int K = DMODEL;

  // XCD-bijective swizzle (nwg = 33*16 = 528, %8==0)
  const int nx   = gridDim.x;               // 33 N-tiles
  const int flat = blockIdx.y * nx + blockIdx.x;
  const int q    = (nx * gridDim.y) >> 3;
  const int swz  = (flat & 7) * q + (flat >> 3);
  const int bm   = swz / nx, bn = swz % nx;

  const int tid  = threadIdx.x;
  const int wave = tid >> 6, lane = tid & 63;
  const int wm   = (wave >> 1) * 128, wn = (wave & 1) * 64;
  const int lrow = lane & 15, khalf = lane >> 4;
  const int cread = (khalf ^ ((lrow >> 1) & 3)) * 8;

  const int srow = wave * 16 + (lane >> 2);
  const int scol = ((lane & 3) ^ ((lane >> 3) & 3)) * 8;
  const unsigned short* Ag = A + (size_t)(bm * 256 + srow) * K + scol;
  const unsigned short* Bg = B + (size_t)(bn * 128 + srow) * K + scol;
  const int lr0 = wave * 16;

  f32x4v acc[8][4];
  #pragma unroll
  for (int i = 0; i < 8; ++i)
    #pragma unroll
    for (int j = 0; j < 4; ++j)
      acc[i][j] = (f32x4v){0.f,0.f,0.f,0.f};

  auto stage = [&](int buf, int k0){
    #pragma unroll
    for (int j = 0; j < 4; ++j)
      gload_lds16(Ag + (size_t)j * 64 * K + k0, &As[buf][j * 64 + lr0][0]);
    #pragma unroll
    for (int j = 0; j < 2; ++j)
      gload_lds16(Bg + (size_t)j * 64 * K + k0, &Bs[buf][j * 64 + lr0][0]);
  };

  const int NT = K >> 5;   // 32
  stage(0, 0);
  stage(1, 32);
  for (int t = 0; t < NT; ++t) {
    const int cur = t & 1;
    if (t + 1 < NT) { asm volatile("s_waitcnt vmcnt(6)" ::: "memory"); }
    else            { asm volatile("s_waitcnt vmcnt(0)" ::: "memory"); }
    __builtin_amdgcn_s_barrier();
    __builtin_amdgcn_sched_barrier(0);
    bf16x8 bfr[4];
    #pragma unroll
    for (int n = 0; n < 4; ++n)
      bfr[n] = *(const bf16x8*)&Bs[cur][wn + n * 16 + lrow][cread];
    __builtin_amdgcn_s_setprio(1);
    #pragma unroll
    for (int mi = 0; mi < 8; ++mi) {
      bf16x8 a = *(const bf16x8*)&As[cur][wm + mi * 16 + lrow][cread];
      #pragma unroll
      for (int n = 0; n < 4; ++n)
        acc[mi][n] = MFMA16(a, bfr[n], acc[mi][n]);
    }
    __builtin_amdgcn_s_setprio(0);
    __builtin_amdgcn_s_barrier();
    __builtin_amdgcn_sched_barrier(0);
    if (t + 2 < NT) stage(cur, (t + 2) << 5);
  }

  // epilogue: col<2048 -> z f32; 2048..4191 -> xbcdt f32 (ld XWIDTH); pad dropped
  const int orow0 = bm * 256 + wm;
  const int ocol0 = bn * 128 + wn;
  #pragma unroll
  for (int mi = 0; mi < 8; ++mi)
    #pragma unroll
    for (int ni = 0; ni < 4; ++ni) {
      int col  = ocol0 + ni * 16 + lrow;
      int rowb = orow0 + mi * 16 + khalf * 4;
      #pragma unroll
      for (int r = 0; r < 4; ++r) {
        int row = rowb + r;
        float v = acc[mi][ni][r];
        if (col < DINNER)        C0[(size_t)row * DINNER + col] = v;
        else if (col < DINPROJ)  C1[(size_t)row * XWIDTH + (col - DINNER)] = v;
      }
    }
}

// ---------------- 128x128 GEMM (out_proj), proven R6 structure ----------------
__global__ __launch_bounds__(256) void gemm_bf16_out(
    const unsigned short* __restrict__ A,
    const unsigned short* __restrict__ B,
    int K, float* __restrict__ C0, int N)
{
  __shared__ unsigned short As[2][128][32];
  __shared__ unsigned short Bs[2][128][32];

  const int nx   = gridDim.x;
  const int flat = blockIdx.y * nx + blockIdx.x;
  const int q    = (nx * gridDim.y) >> 3;
  const int swz  = (flat & 7) * q + (flat >> 3);
  const int bm   = swz / nx, bn = swz % nx;

  const int tid  = threadIdx.x;
  const int wave = tid >> 6, lane = tid & 63;
  const int wm   = (wave >> 1) * 64, wn = (wave & 1) * 64;
  const int lrow = lane & 15, khalf = lane >> 4;
  const int cread = (khalf ^ ((lrow >> 1) & 3)) * 8;

  const int srow = wave * 16 + (lane >> 2);
  const int scol = ((lane & 3) ^ ((lane >> 3) & 3)) * 8;
  const unsigned short* Ag = A + (size_t)(bm * 128 + srow) * K + scol;
  const unsigned short* Bg = B + (size_t)(bn * 128 + srow) * K + scol;
  const int lr0 = wave * 16;

  f32x4v acc[4][4];
  #pragma unroll
  for (int i = 0; i < 4; ++i)
    #pragma unroll
    for (int j = 0; j < 4; ++j)
      acc[i][j] = (f32x4v){0.f,0.f,0.f,0.f};

  auto stage = [&](int buf, int k0){
    gload_lds16(Ag + k0,                   &As[buf][lr0][0]);
    gload_lds16(Ag + k0 + (size_t)64 * K,  &As[buf][64 + lr0][0]);
    gload_lds16(Bg + k0,                   &Bs[buf][lr0][0]);
    gload_lds16(Bg + k0 + (size_t)64 * K,  &Bs[buf][64 + lr0][0]);
  };

  const int NT = K >> 5;
  stage(0, 0);
  stage(1, 32);
  for (int t = 0; t < NT; ++t) {
    const int cur = t & 1;
    if (t + 1 < NT) { asm volatile("s_waitcnt vmcnt(4)" ::: "memory"); }
    else            { asm volatile("s_waitcnt vmcnt(0)" ::: "memory"); }
    __builtin_amdgcn_s_barrier();
    __builtin_amdgcn_sched_barrier(0);
    bf16x8 af[4], bfr[4];
    #pragma unroll
    for (int i = 0; i < 4; ++i) {
      af[i]  = *(const bf16x8*)&As[cur][wm + i * 16 + lrow][cread];
      bfr[i] = *(const bf16x8*)&Bs[cur][wn + i * 16 + lrow][cread];
    }
    __builtin_amdgcn_s_setprio(1);
    #pragma unroll
    for (int mi = 0; mi < 4; ++mi)
      #pragma unroll
      for (int ni = 0; ni < 4; ++ni)
        acc[mi][ni] = MFMA16(af[mi], bfr[ni], acc[mi][ni]);
    __builtin_amdgcn_s_setprio(0);
    __builtin_amdgcn_s_barrier();
    __builtin_amdgcn_sched_barrier(0);
    if (t + 2 < NT) stage(cur, (t + 2) << 5);
  }

  const int orow0 = bm * 128 + wm;
  const int ocol0 = bn * 128 + wn;
  #pragma unroll
  for (int mi = 0; mi < 4; ++mi)
    #pragma unroll
    for (int ni = 0; ni < 4; ++ni) {
      int col  = ocol0 + ni * 16 + lrow;
      int rowb = orow0 + mi * 16 + khalf * 4;
      #pragma unroll
      for (int r = 0; r < 4; ++r)
        C0[(size_t)(rowb + r) * N + col] = acc[mi][ni][r];
    }
}

// ---------------- conv1d + dt, x4-channel vectorized ----------------
__global__ __launch_bounds__(256) void conv_dt_kernel(
    const float* __restrict__ xbcdt,
    const float* __restrict__ conv_w, const float* __restrict__ conv_b,
    const float* __restrict__ dt_bias,
    unsigned short* __restrict__ xconv, float* __restrict__ dtout)
{
  int idx = blockIdx.x * 256 + threadIdx.x;     // BL * 536 total
  if (idx >= BL * XW4) return;
  int c4 = idx % XW4;
  int bl = idx / XW4;
  int l  = bl & (SEQLEN - 1);
  int ch = c4 * 4;
  if (ch < CONVDIM) {
    f4 acc = *(const f4*)&conv_b[ch];
    #pragma unroll
    for (int j = 0; j < 4; ++j) {
      int ls = l - 3 + j;
      f4 x = (ls >= 0) ? *(const f4*)&xbcdt[(size_t)(bl - 3 + j) * XWIDTH + ch]
                       : (f4){0.f,0.f,0.f,0.f};
      #pragma unroll
      for (int k = 0; k < 4; ++k) acc[k] += conv_w[(ch + k) * 4 + j] * x[k];
    }
    u16x4 o;
    #pragma unroll
    for (int k = 0; k < 4; ++k) {
      float s = acc[k] / (1.f + __expf(-acc[k]));
      o[k] = f2bf(s);
    }
    *(u16x4*)&xconv[(size_t)bl * CONVDIM + ch] = o;
  } else {
    int h = ch - CONVDIM;
    f4 x = *(const f4*)&xbcdt[(size_t)bl * XWIDTH + ch];
    f4 bz = *(const f4*)&dt_bias[h];
    f4 o;
    #pragma unroll
    for (int k = 0; k < 4; ++k) {
      float v = x[k] + bz[k];
      o[k] = (v > 20.f) ? v : log1pf(__expf(v));
    }
    *(f4*)&dtout[(size_t)bl * NHEADS + h] = o;
  }
}

// ---------------- SSD phase A: Acum scan + chunk states ----------------
__global__ __launch_bounds__(256) void ssd_phaseA(
    const unsigned short* __restrict__ xconv, const float* __restrict__ dt,
    const float* __restrict__ A_log,
    float* __restrict__ acum, float* __restrict__ decay, float* __restrict__ states)
{
  int bc = blockIdx.x, h = blockIdx.y;
  int b = bc >> 3;
  int t = threadIdx.x;
  __shared__ float sAc[256], sCoef[256], sDt[256];
  __shared__ float sB[256][16];
  __shared__ float sX[256][32];
  int rowbase = b * SEQLEN + (bc & 7) * CHUNK;
  float dtv = dt[(rowbase + t) * NHEADS + h];
  float Av  = -__expf(A_log[h]);
  sAc[t] = dtv * Av; sDt[t] = dtv;
  for (int i = t; i < 256 * 16; i += 256) { int l = i >> 4, n = i & 15; sB[l][n] = bf2f(xconv[(size_t)(rowbase + l) * CONVDIM + DINNER + n]); }
  for (int i = t; i < 256 * 32; i += 256) { int l = i >> 5, p = i & 31; sX[l][p] = bf2f(xconv[(size_t)(rowbase + l) * CONVDIM + h * 32 + p]); }
  __syncthreads();
  for (int off = 1; off < 256; off <<= 1) {
    float add = (t >= off) ? sAc[t - off] : 0.f;
    __syncthreads();
    sAc[t] += add;
    __syncthreads();
  }
  int bch = bc * 64 + h;
  acum[(size_t)bch * 256 + t] = sAc[t];
  float last = sAc[255];
  if (t == 0) decay[bch] = __expf(last);
  sCoef[t] = sDt[t] * __expf(last - sAc[t]);
  __syncthreads();
  #pragma unroll
  for (int o = 0; o < 2; ++o) {
    int oi = t + o * 256;
    int p = oi >> 4, n = oi & 15;
    float acc = 0.f;
    for (int l = 0; l < 256; ++l) acc += sCoef[l] * sB[l][n] * sX[l][p];
    states[(size_t)bch * 512 + oi] = acc;
  }
}

// ---------------- SSD phase B: sequential chunk scan ----------------
__global__ void ssd_phaseB(const float* __restrict__ states, const float* __restrict__ decay,
                           float* __restrict__ prev)
{
  int bh = blockIdx.x;
  int b = bh >> 6, h = bh & 63;
  int t = threadIdx.x;           // 512
  float carry = 0.f;
  for (int c = 0; c < NCHUNK; ++c) {
    int bch = (b * 8 + c) * 64 + h;
    size_t base = (size_t)bch * 512 + t;
    prev[base] = carry;
    carry = decay[bch] * carry + states[base];
  }
}

// ---------------- SSD phase C (MFMA), y output bf16 ----------------
__global__ __launch_bounds__(256, 2) void ssd_phaseC_mfma(
    const unsigned short* __restrict__ xconv, const float* __restrict__ dt,
    const float* __restrict__ acum, const float* __restrict__ prev,
    const float* __restrict__ Dvec, unsigned short* __restrict__ ybf)
{
  const int bc = blockIdx.x, h = blockIdx.y;
  const int b = bc >> 3;
  const int rowbase = b * SEQLEN + (bc & 7) * CHUNK;
  const int bch = bc * 64 + h;
  const int tid = threadIdx.x, wave = tid >> 6, lane = tid & 63;
  const int l16 = lane & 15, khalf = lane >> 4;

  __shared__ float sAcum[256];
  __shared__ __bf16 sXT[32][264];
  __shared__ __bf16 sP[4][2][16][40];

  if (tid < 256) sAcum[tid] = acum[(size_t)bch * 256 + tid];
  {
    int l  = tid >> 3;
    int p0 = (tid & 7) * 4;
    #pragma unroll
    for (int pass = 0; pass < 8; ++pass) {
      int ls = l + pass * 32;
      const unsigned short* xr = xconv + (size_t)(rowbase + ls) * CONVDIM + h * 32 + p0;
      u16x4 v = *(const u16x4*)xr;
      float dtl = dt[(rowbase + ls) * NHEADS + h];
      #pragma unroll
      for (int j = 0; j < 4; ++j) sXT[p0 + j][ls] = (__bf16)(bf2f(v[j]) * dtl);
    }
  }

  const bool kv = (khalf < 2);
  bf16x8 bfr[16], cfr[4], pvf[2];
  #pragma unroll
  for (int i = 0; i < 16; ++i)
    bfr[i] = bf16x8_load(xconv + (size_t)(rowbase + i * 16 + l16) * CONVDIM + DINNER + khalf * 8, kv);
  #pragma unroll
  for (int t = 0; t < 4; ++t)
    cfr[t] = bf16x8_load(xconv + (size_t)(rowbase + (wave + 4 * t) * 16 + l16) * CONVDIM + DINNER + DSTATE + khalf * 8, kv);
  #pragma unroll
  for (int pt = 0; pt < 2; ++pt)
    pvf[pt] = f32x8_to_frag(prev + (size_t)bch * 512 + (pt * 16 + l16) * 16 + khalf * 8, kv);
  __syncthreads();

  const float Dh = Dvec[h];
  #pragma unroll
  for (int t = 0; t < 4; ++t) {
    const int LT = wave + 4 * t;
    const int lbase = LT * 16;
    float al[4], el[4];
    #pragma unroll
    for (int r = 0; r < 4; ++r) { al[r] = sAcum[lbase + khalf * 4 + r]; el[r] = __expf(al[r]); }
    f32x4v y0 = MFMA16(cfr[t], pvf[0], ((f32x4v){0.f,0.f,0.f,0.f}));
    f32x4v y1 = MFMA16(cfr[t], pvf[1], ((f32x4v){0.f,0.f,0.f,0.f}));
    #pragma unroll
    for (int r = 0; r < 4; ++r) { y0[r] *= el[r]; y1[r] *= el[r]; }

    #pragma unroll
    for (int kp = 0; kp < 8; ++kp) {
      if (2 * kp <= LT) {
        f32x4v s0 = MFMA16(cfr[t], bfr[2 * kp],     ((f32x4v){0.f,0.f,0.f,0.f}));
        f32x4v s1 = MFMA16(cfr[t], bfr[2 * kp + 1], ((f32x4v){0.f,0.f,0.f,0.f}));
        const int buf = kp & 1;
        #pragma unroll
        for (int r = 0; r < 4; ++r) {
          int l  = lbase + khalf * 4 + r;
          int sA = 2 * kp * 16 + l16;
          int sB2 = sA + 16;
          float p0 = (sA  <= l) ? s0[r] * __expf(al[r] - sAcum[sA])  : 0.f;
          float p1 = (sB2 <= l) ? s1[r] * __expf(al[r] - sAcum[sB2]) : 0.f;
          sP[wave][buf][khalf * 4 + r][l16]      = (__bf16)p0;
          sP[wave][buf][khalf * 4 + r][16 + l16] = (__bf16)p1;
        }
        bf16x8 pa  = *(const bf16x8*)&sP[wave][buf][l16][khalf * 8];
        bf16x8 xf0 = *(const bf16x8*)&sXT[l16][kp * 32 + khalf * 8];
        bf16x8 xf1 = *(const bf16x8*)&sXT[16 + l16][kp * 32 + khalf * 8];
        y0 = MFMA16(pa, xf0, y0);
        y1 = MFMA16(pa, xf1, y1);
      }
    }

    #pragma unroll
    for (int r = 0; r < 4; ++r) {
      int lg = rowbase + lbase + khalf * 4 + r;
      const unsigned short* xr = xconv + (size_t)lg * CONVDIM + h * 32;
      unsigned short* yr = ybf + (size_t)lg * DINNER + h * 32;
      yr[l16]      = f2bf(y0[r] + Dh * bf2f(xr[l16]));
      yr[16 + l16] = f2bf(y1[r] + Dh * bf2f(xr[16 + l16]));
    }
  }
}

// ---------------- gate (silu(z)) + RMSNorm -> bf16 (y input bf16) ----------------
__global__ __launch_bounds__(256) void gate_norm(const unsigned short* __restrict__ ybf,
    const float* __restrict__ z, const float* __restrict__ norm_w,
    unsigned short* __restrict__ ynbf)
{
  int row = blockIdx.x, t = threadIdx.x;
  const unsigned short* yr = ybf + (size_t)row * DINNER + t * 8;
  const float* zr = z + (size_t)row * DINNER + t * 8;
  s16x8 yv = *(const s16x8*)yr;
  f4 z0 = *(const f4*)zr;
  f4 z1 = *(const f4*)(zr + 4);
  float vals[8];
  float ss = 0.f;
  #pragma unroll
  for (int k = 0; k < 8; ++k) {
    float zv = (k < 4) ? z0[k] : z1[k - 4];
    float g  = zv / (1.f + __expf(-zv));
    float v  = bf2f((unsigned short)yv[k]) * g;
    vals[k] = v; ss += v * v;
  }
  #pragma unroll
  for (int o = 1; o < 64; o <<= 1) ss += __shfl_xor(ss, o);
  __shared__ float sred[4];
  if ((t & 63) == 0) sred[t >> 6] = ss;
  __syncthreads();
  float tot = sred[0] + sred[1] + sred[2] + sred[3];
  float scale = rsqrtf(tot * (1.f / DINNER) + 1e-5f);
  const float* nw = norm_w + t * 8;
  s16x8 o;
  #pragma unroll
  for (int k = 0; k < 8; ++k) o[k] = (short)f2bf(vals[k] * scale * nw[k]);
  *(s16x8*)&ynbf[(size_t)row * DINNER + t * 8] = o;
}

// ---------------- launch ----------------
extern "C" void kernel_launch(void* const* d_in, const int* in_sizes, int n_in,
                              void* d_out, int out_size, void* d_ws, size_t ws_size,
                              hipStream_t stream)
{
  const float* u       = (const float*)d_in[0];
  const float* W_in    = (const float*)d_in[1];
  const float* conv_w  = (const float*)d_in[2];
  const float* conv_b  = (const float*)d_in[3];
  const float* dt_bias = (const float*)d_in[4];
  const float* A_log   = (const float*)d_in[5];
  const float* Dv      = (const float*)d_in[6];
  const float* norm_w  = (const float*)d_in[7];
  const float* W_out   = (const float*)d_in[8];

  float* out  = (float*)d_out;
  float* zout = out + (size_t)BL * DMODEL;

  char* ws = (char*)d_ws;
  size_t off = 0;
  auto alloc = [&](size_t bytes){ size_t o = off; off += (bytes + 255) & ~(size_t)255; return o; };
  size_t o_ubf    = alloc((size_t)BL * DMODEL * 2);
  size_t o_wbf    = alloc((size_t)NPAD * DMODEL * 2);
  size_t o_xbcdt  = alloc((size_t)BL * XWIDTH * 4);    // f32; later reused as ybf
  size_t o_xconv  = alloc((size_t)BL * CONVDIM * 2);   // bf16
  size_t o_dt     = alloc((size_t)BL * NHEADS * 4);
  size_t o_acum   = alloc((size_t)1024 * 256 * 4);
  size_t o_decay  = alloc((size_t)1024 * 4);
  size_t o_states = alloc((size_t)1024 * 512 * 4);
  size_t o_prev   = alloc((size_t)1024 * 512 * 4);
  size_t o_ynbf   = alloc((size_t)BL * DINNER * 2);

  unsigned short* ubf    = (unsigned short*)(ws + o_ubf);
  unsigned short* wbf    = (unsigned short*)(ws + o_wbf);
  float*          xbcdt  = (float*)(ws + o_xbcdt);
  unsigned short* xconv  = (unsigned short*)(ws + o_xconv);
  float*          dtws   = (float*)(ws + o_dt);
  float*          acum   = (float*)(ws + o_acum);
  float*          decay  = (float*)(ws + o_decay);
  float*          states = (float*)(ws + o_states);
  float*          prevb  = (float*)(ws + o_prev);
  unsigned short* ynbf   = (unsigned short*)(ws + o_ynbf);
  unsigned short* woutbf = ubf;                        // reuse
  unsigned short* ybf    = (unsigned short*)(ws + o_xbcdt);  // reuse xbcdt region

  cast_f32_bf16<<<(BL * DMODEL) / 256, 256, 0, stream>>>(u, ubf, BL * DMODEL);
  cast_win_pad<<<(NPAD * DMODEL) / 256, 256, 0, stream>>>(W_in, wbf);

  gemm_in_256128<<<dim3(NPAD / 128, BL / 256), 256, 0, stream>>>(ubf, wbf, zout, xbcdt);

  conv_dt_kernel<<<(BL * XW4 + 255) / 256, 256, 0, stream>>>(xbcdt, conv_w, conv_b, dt_bias, xconv, dtws);

  ssd_phaseA<<<dim3(16, 64), 256, 0, stream>>>(xconv, dtws, A_log, acum, decay, states);
  ssd_phaseB<<<128, 512, 0, stream>>>(states, decay, prevb);
  ssd_phaseC_mfma<<<dim3(16, 64), 256, 0, stream>>>(xconv, dtws, acum, prevb, Dv, ybf);

  gate_norm<<<BL, 256, 0, stream>>>(ybf, zout, norm_w, ynbf);

  cast_f32_bf16<<<(DMODEL * DINNER) / 256, 256, 0, stream>>>(W_out, woutbf, DMODEL * DINNER);

  gemm_bf16_out<<<dim3(DMODEL / 128, BL / 128), 256, 0, stream>>>(ynbf, woutbf, DINNER, out, DMODEL);
}

// Round 11
// 236.048 us; speedup vs baseline: 1.0808x; 1.0808x over previous
//
#include <hip/hip_runtime.h>

#define BATCH   2
#define SEQLEN  2048
#define DMODEL  1024
#define DINNER  2048
#define NHEADS  64
#define HEADDIM 32
#define DSTATE  16
#define CONVDIM 2080
#define DINPROJ 4192
#define NPAD    4224
#define CHUNK   256
#define NCHUNK  8
#define BL      (BATCH*SEQLEN)   // 4096
#define XWIDTH  2144             // CONVDIM + NHEADS
#define XW4     (XWIDTH/4)       // 536

#define N_U     (BL*DMODEL)      // 4194304
#define N_WIN   (NPAD*DMODEL)    // 4325376
#define N_WOUT  (DMODEL*DINNER)  // 2097152

typedef float          f4    __attribute__((ext_vector_type(4)));
typedef short          s16x8 __attribute__((ext_vector_type(8)));
typedef unsigned short u16x4 __attribute__((ext_vector_type(4)));
typedef __bf16         bf16x8 __attribute__((ext_vector_type(8)));
typedef float          f32x4v __attribute__((ext_vector_type(4)));

#define MFMA16(a,b,c) __builtin_amdgcn_mfma_f32_16x16x32_bf16((a),(b),(c),0,0,0)

__device__ __forceinline__ unsigned short f2bf(float f){
  unsigned int u = __float_as_uint(f);
  u += 0x7FFFu + ((u >> 16) & 1u);
  return (unsigned short)(u >> 16);
}
__device__ __forceinline__ float bf2f(unsigned short u){
  return __uint_as_float(((unsigned int)u) << 16);
}

__device__ __forceinline__ void gload_lds16(const void* g, void* l){
  __builtin_amdgcn_global_load_lds((const __attribute__((address_space(1))) unsigned int*)g,
                                   (__attribute__((address_space(3))) unsigned int*)l,
                                   16, 0, 0);
}

__device__ __forceinline__ bf16x8 f32x8_to_frag(const float* src, bool valid){
  bf16x8 r;
  if (valid) {
    f4 a = *(const f4*)src;
    f4 c = *(const f4*)(src + 4);
    r[0]=(__bf16)a[0]; r[1]=(__bf16)a[1]; r[2]=(__bf16)a[2]; r[3]=(__bf16)a[3];
    r[4]=(__bf16)c[0]; r[5]=(__bf16)c[1]; r[6]=(__bf16)c[2]; r[7]=(__bf16)c[3];
  } else {
    r[0]=(__bf16)0.f; r[1]=(__bf16)0.f; r[2]=(__bf16)0.f; r[3]=(__bf16)0.f;
    r[4]=(__bf16)0.f; r[5]=(__bf16)0.f; r[6]=(__bf16)0.f; r[7]=(__bf16)0.f;
  }
  return r;
}

__device__ __forceinline__ bf16x8 bf16x8_load(const unsigned short* src, bool valid){
  if (valid) {
    s16x8 v = *(const s16x8*)src;
    return *(bf16x8*)&v;
  }
  bf16x8 r;
  r[0]=(__bf16)0.f; r[1]=(__bf16)0.f; r[2]=(__bf16)0.f; r[3]=(__bf16)0.f;
  r[4]=(__bf16)0.f; r[5]=(__bf16)0.f; r[6]=(__bf16)0.f; r[7]=(__bf16)0.f;
  return r;
}

// ---------------- fused casts: u, W_in (padded), W_out -> bf16 ----------------
__global__ void cast_all(const float* __restrict__ u, const float* __restrict__ W_in,
                         const float* __restrict__ W_out,
                         unsigned short* __restrict__ ubf, unsigned short* __restrict__ wbf,
                         unsigned short* __restrict__ woutbf){
  int i = blockIdx.x * 256 + threadIdx.x;
  if (i < N_U) {
    ubf[i] = f2bf(u[i]);
  } else if (i < N_U + N_WIN) {
    int j = i - N_U;
    int r = j >> 10;
    wbf[j] = (r < DINPROJ) ? f2bf(W_in[j]) : (unsigned short)0;
  } else {
    int j = i - N_U - N_WIN;
    woutbf[j] = f2bf(W_out[j]);
  }
}

// ---------------- bf16 MFMA GEMM 128x128, proven R6 structure ----------------
// T4 counted-vmcnt 2-deep pipeline; conflict-free chunk-XOR LDS swizzle; XCD swizzle.
// MODE 0: in_proj epilogue split (z f32 / xbcdt f32); MODE 1: plain store ld N.
template<int MODE>
__global__ __launch_bounds__(256) void gemm_bf16(
    const unsigned short* __restrict__ A,
    const unsigned short* __restrict__ B,
    int K, float* __restrict__ C0, float* __restrict__ C1, int N)
{
  __shared__ unsigned short As[2][128][32];
  __shared__ unsigned short Bs[2][128][32];

  const int nx   = gridDim.x;
  const int flat = blockIdx.y * nx + blockIdx.x;
  const int q    = (nx * gridDim.y) >> 3;
  const int swz  = (flat & 7) * q + (flat >> 3);
  const int bm   = swz / nx, bn = swz % nx;

  const int tid  = threadIdx.x;
  const int wave = tid >> 6, lane = tid & 63;
  const int wm   = (wave >> 1) * 64, wn = (wave & 1) * 64;
  const int lrow = lane & 15, khalf = lane >> 4;
  const int cread = (khalf ^ ((lrow >> 1) & 3)) * 8;

  const int srow = wave * 16 + (lane >> 2);
  const int scol = ((lane & 3) ^ ((lane >> 3) & 3)) * 8;
  const unsigned short* Ag = A + (size_t)(bm * 128 + srow) * K + scol;
  const unsigned short* Bg = B + (size_t)(bn * 128 + srow) * K + scol;
  const int lr0 = wave * 16;

  f32x4v acc[4][4];
  #pragma unroll
  for (int i = 0; i < 4; ++i)
    #pragma unroll
    for (int j = 0; j < 4; ++j)
      acc[i][j] = (f32x4v){0.f,0.f,0.f,0.f};

  auto stage = [&](int buf, int k0){
    gload_lds16(Ag + k0,                   &As[buf][lr0][0]);
    gload_lds16(Ag + k0 + (size_t)64 * K,  &As[buf][64 + lr0][0]);
    gload_lds16(Bg + k0,                   &Bs[buf][lr0][0]);
    gload_lds16(Bg + k0 + (size_t)64 * K,  &Bs[buf][64 + lr0][0]);
  };

  const int NT = K >> 5;
  stage(0, 0);
  stage(1, 32);
  for (int t = 0; t < NT; ++t) {
    const int cur = t & 1;
    if (t + 1 < NT) { asm volatile("s_waitcnt vmcnt(4)" ::: "memory"); }
    else            { asm volatile("s_waitcnt vmcnt(0)" ::: "memory"); }
    __builtin_amdgcn_s_barrier();
    __builtin_amdgcn_sched_barrier(0);
    bf16x8 af[4], bfr[4];
    #pragma unroll
    for (int i = 0; i < 4; ++i) {
      af[i]  = *(const bf16x8*)&As[cur][wm + i * 16 + lrow][cread];
      bfr[i] = *(const bf16x8*)&Bs[cur][wn + i * 16 + lrow][cread];
    }
    __builtin_amdgcn_s_setprio(1);
    #pragma unroll
    for (int mi = 0; mi < 4; ++mi)
      #pragma unroll
      for (int ni = 0; ni < 4; ++ni)
        acc[mi][ni] = MFMA16(af[mi], bfr[ni], acc[mi][ni]);
    __builtin_amdgcn_s_setprio(0);
    __builtin_amdgcn_s_barrier();
    __builtin_amdgcn_sched_barrier(0);
    if (t + 2 < NT) stage(cur, (t + 2) << 5);
  }

  const int orow0 = bm * 128 + wm;
  const int ocol0 = bn * 128 + wn;
  #pragma unroll
  for (int mi = 0; mi < 4; ++mi)
    #pragma unroll
    for (int ni = 0; ni < 4; ++ni) {
      int col  = ocol0 + ni * 16 + lrow;
      int rowb = orow0 + mi * 16 + khalf * 4;
      #pragma unroll
      for (int r = 0; r < 4; ++r) {
        int row = rowb + r;
        float v = acc[mi][ni][r];
        if (MODE == 0) {
          if (col < DINNER)        C0[(size_t)row * DINNER + col] = v;
          else if (col < DINPROJ)  C1[(size_t)row * XWIDTH + (col - DINNER)] = v;
        } else {
          C0[(size_t)row * N + col] = v;
        }
      }
    }
}

// ---------------- conv1d + dt, x4-channel vectorized ----------------
__global__ __launch_bounds__(256) void conv_dt_kernel(
    const float* __restrict__ xbcdt,
    const float* __restrict__ conv_w, const float* __restrict__ conv_b,
    const float* __restrict__ dt_bias,
    unsigned short* __restrict__ xconv, float* __restrict__ dtout)
{
  int idx = blockIdx.x * 256 + threadIdx.x;     // BL * 536 total
  if (idx >= BL * XW4) return;
  int c4 = idx % XW4;
  int bl = idx / XW4;
  int l  = bl & (SEQLEN - 1);
  int ch = c4 * 4;
  if (ch < CONVDIM) {
    f4 acc = *(const f4*)&conv_b[ch];
    #pragma unroll
    for (int j = 0; j < 4; ++j) {
      int ls = l - 3 + j;
      f4 x = (ls >= 0) ? *(const f4*)&xbcdt[(size_t)(bl - 3 + j) * XWIDTH + ch]
                       : (f4){0.f,0.f,0.f,0.f};
      #pragma unroll
      for (int k = 0; k < 4; ++k) acc[k] += conv_w[(ch + k) * 4 + j] * x[k];
    }
    u16x4 o;
    #pragma unroll
    for (int k = 0; k < 4; ++k) {
      float s = acc[k] / (1.f + __expf(-acc[k]));
      o[k] = f2bf(s);
    }
    *(u16x4*)&xconv[(size_t)bl * CONVDIM + ch] = o;
  } else {
    int h = ch - CONVDIM;
    f4 x = *(const f4*)&xbcdt[(size_t)bl * XWIDTH + ch];
    f4 bz = *(const f4*)&dt_bias[h];
    f4 o;
    #pragma unroll
    for (int k = 0; k < 4; ++k) {
      float v = x[k] + bz[k];
      o[k] = (v > 20.f) ? v : log1pf(__expf(v));
    }
    *(f4*)&dtout[(size_t)bl * NHEADS + h] = o;
  }
}

// ---------------- SSD phase A: Acum scan + chunk states ----------------
__global__ __launch_bounds__(256) void ssd_phaseA(
    const unsigned short* __restrict__ xconv, const float* __restrict__ dt,
    const float* __restrict__ A_log,
    float* __restrict__ acum, float* __restrict__ decay, float* __restrict__ states)
{
  int bc = blockIdx.x, h = blockIdx.y;
  int b = bc >> 3;
  int t = threadIdx.x;
  __shared__ float sAc[256], sCoef[256], sDt[256];
  __shared__ float sB[256][16];
  __shared__ float sX[256][32];
  int rowbase = b * SEQLEN + (bc & 7) * CHUNK;
  float dtv = dt[(rowbase + t) * NHEADS + h];
  float Av  = -__expf(A_log[h]);
  sAc[t] = dtv * Av; sDt[t] = dtv;
  for (int i = t; i < 256 * 16; i += 256) { int l = i >> 4, n = i & 15; sB[l][n] = bf2f(xconv[(size_t)(rowbase + l) * CONVDIM + DINNER + n]); }
  for (int i = t; i < 256 * 32; i += 256) { int l = i >> 5, p = i & 31; sX[l][p] = bf2f(xconv[(size_t)(rowbase + l) * CONVDIM + h * 32 + p]); }
  __syncthreads();
  for (int off = 1; off < 256; off <<= 1) {
    float add = (t >= off) ? sAc[t - off] : 0.f;
    __syncthreads();
    sAc[t] += add;
    __syncthreads();
  }
  int bch = bc * 64 + h;
  acum[(size_t)bch * 256 + t] = sAc[t];
  float last = sAc[255];
  if (t == 0) decay[bch] = __expf(last);
  sCoef[t] = sDt[t] * __expf(last - sAc[t]);
  __syncthreads();
  #pragma unroll
  for (int o = 0; o < 2; ++o) {
    int oi = t + o * 256;
    int p = oi >> 4, n = oi & 15;
    float acc = 0.f;
    for (int l = 0; l < 256; ++l) acc += sCoef[l] * sB[l][n] * sX[l][p];
    states[(size_t)bch * 512 + oi] = acc;
  }
}

// ---------------- SSD phase B: sequential chunk scan ----------------
__global__ void ssd_phaseB(const float* __restrict__ states, const float* __restrict__ decay,
                           float* __restrict__ prev)
{
  int bh = blockIdx.x;
  int b = bh >> 6, h = bh & 63;
  int t = threadIdx.x;           // 512
  float carry = 0.f;
  for (int c = 0; c < NCHUNK; ++c) {
    int bch = (b * 8 + c) * 64 + h;
    size_t base = (size_t)bch * 512 + t;
    prev[base] = carry;
    carry = decay[bch] * carry + states[base];
  }
}

// ---------------- SSD phase C (MFMA), y output bf16 ----------------
__global__ __launch_bounds__(256, 2) void ssd_phaseC_mfma(
    const unsigned short* __restrict__ xconv, const float* __restrict__ dt,
    const float* __restrict__ acum, const float* __restrict__ prev,
    const float* __restrict__ Dvec, unsigned short* __restrict__ ybf)
{
  const int bc = blockIdx.x, h = blockIdx.y;
  const int b = bc >> 3;
  const int rowbase = b * SEQLEN + (bc & 7) * CHUNK;
  const int bch = bc * 64 + h;
  const int tid = threadIdx.x, wave = tid >> 6, lane = tid & 63;
  const int l16 = lane & 15, khalf = lane >> 4;

  __shared__ float sAcum[256];
  __shared__ __bf16 sXT[32][264];
  __shared__ __bf16 sP[4][2][16][40];

  if (tid < 256) sAcum[tid] = acum[(size_t)bch * 256 + tid];
  {
    int l  = tid >> 3;
    int p0 = (tid & 7) * 4;
    #pragma unroll
    for (int pass = 0; pass < 8; ++pass) {
      int ls = l + pass * 32;
      const unsigned short* xr = xconv + (size_t)(rowbase + ls) * CONVDIM + h * 32 + p0;
      u16x4 v = *(const u16x4*)xr;
      float dtl = dt[(rowbase + ls) * NHEADS + h];
      #pragma unroll
      for (int j = 0; j < 4; ++j) sXT[p0 + j][ls] = (__bf16)(bf2f(v[j]) * dtl);
    }
  }

  const bool kv = (khalf < 2);
  bf16x8 bfr[16], cfr[4], pvf[2];
  #pragma unroll
  for (int i = 0; i < 16; ++i)
    bfr[i] = bf16x8_load(xconv + (size_t)(rowbase + i * 16 + l16) * CONVDIM + DINNER + khalf * 8, kv);
  #pragma unroll
  for (int t = 0; t < 4; ++t)
    cfr[t] = bf16x8_load(xconv + (size_t)(rowbase + (wave + 4 * t) * 16 + l16) * CONVDIM + DINNER + DSTATE + khalf * 8, kv);
  #pragma unroll
  for (int pt = 0; pt < 2; ++pt)
    pvf[pt] = f32x8_to_frag(prev + (size_t)bch * 512 + (pt * 16 + l16) * 16 + khalf * 8, kv);
  __syncthreads();

  const float Dh = Dvec[h];
  #pragma unroll
  for (int t = 0; t < 4; ++t) {
    const int LT = wave + 4 * t;
    const int lbase = LT * 16;
    float al[4], el[4];
    #pragma unroll
    for (int r = 0; r < 4; ++r) { al[r] = sAcum[lbase + khalf * 4 + r]; el[r] = __expf(al[r]); }
    f32x4v y0 = MFMA16(cfr[t], pvf[0], ((f32x4v){0.f,0.f,0.f,0.f}));
    f32x4v y1 = MFMA16(cfr[t], pvf[1], ((f32x4v){0.f,0.f,0.f,0.f}));
    #pragma unroll
    for (int r = 0; r < 4; ++r) { y0[r] *= el[r]; y1[r] *= el[r]; }

    #pragma unroll
    for (int kp = 0; kp < 8; ++kp) {
      if (2 * kp <= LT) {
        f32x4v s0 = MFMA16(cfr[t], bfr[2 * kp],     ((f32x4v){0.f,0.f,0.f,0.f}));
        f32x4v s1 = MFMA16(cfr[t], bfr[2 * kp + 1], ((f32x4v){0.f,0.f,0.f,0.f}));
        const int buf = kp & 1;
        #pragma unroll
        for (int r = 0; r < 4; ++r) {
          int l  = lbase + khalf * 4 + r;
          int sA = 2 * kp * 16 + l16;
          int sB2 = sA + 16;
          float p0 = (sA  <= l) ? s0[r] * __expf(al[r] - sAcum[sA])  : 0.f;
          float p1 = (sB2 <= l) ? s1[r] * __expf(al[r] - sAcum[sB2]) : 0.f;
          sP[wave][buf][khalf * 4 + r][l16]      = (__bf16)p0;
          sP[wave][buf][khalf * 4 + r][16 + l16] = (__bf16)p1;
        }
        bf16x8 pa  = *(const bf16x8*)&sP[wave][buf][l16][khalf * 8];
        bf16x8 xf0 = *(const bf16x8*)&sXT[l16][kp * 32 + khalf * 8];
        bf16x8 xf1 = *(const bf16x8*)&sXT[16 + l16][kp * 32 + khalf * 8];
        y0 = MFMA16(pa, xf0, y0);
        y1 = MFMA16(pa, xf1, y1);
      }
    }

    #pragma unroll
    for (int r = 0; r < 4; ++r) {
      int lg = rowbase + lbase + khalf * 4 + r;
      const unsigned short* xr = xconv + (size_t)lg * CONVDIM + h * 32;
      unsigned short* yr = ybf + (size_t)lg * DINNER + h * 32;
      yr[l16]      = f2bf(y0[r] + Dh * bf2f(xr[l16]));
      yr[16 + l16] = f2bf(y1[r] + Dh * bf2f(xr[16 + l16]));
    }
  }
}

// ---------------- gate (silu(z)) + RMSNorm -> bf16 (y input bf16) ----------------
__global__ __launch_bounds__(256) void gate_norm(const unsigned short* __restrict__ ybf,
    const float* __restrict__ z, const float* __restrict__ norm_w,
    unsigned short* __restrict__ ynbf)
{
  int row = blockIdx.x, t = threadIdx.x;
  const unsigned short* yr = ybf + (size_t)row * DINNER + t * 8;
  const float* zr = z + (size_t)row * DINNER + t * 8;
  s16x8 yv = *(const s16x8*)yr;
  f4 z0 = *(const f4*)zr;
  f4 z1 = *(const f4*)(zr + 4);
  float vals[8];
  float ss = 0.f;
  #pragma unroll
  for (int k = 0; k < 8; ++k) {
    float zv = (k < 4) ? z0[k] : z1[k - 4];
    float g  = zv / (1.f + __expf(-zv));
    float v  = bf2f((unsigned short)yv[k]) * g;
    vals[k] = v; ss += v * v;
  }
  #pragma unroll
  for (int o = 1; o < 64; o <<= 1) ss += __shfl_xor(ss, o);
  __shared__ float sred[4];
  if ((t & 63) == 0) sred[t >> 6] = ss;
  __syncthreads();
  float tot = sred[0] + sred[1] + sred[2] + sred[3];
  float scale = rsqrtf(tot * (1.f / DINNER) + 1e-5f);
  const float* nw = norm_w + t * 8;
  s16x8 o;
  #pragma unroll
  for (int k = 0; k < 8; ++k) o[k] = (short)f2bf(vals[k] * scale * nw[k]);
  *(s16x8*)&ynbf[(size_t)row * DINNER + t * 8] = o;
}

// ---------------- launch ----------------
extern "C" void kernel_launch(void* const* d_in, const int* in_sizes, int n_in,
                              void* d_out, int out_size, void* d_ws, size_t ws_size,
                              hipStream_t stream)
{
  const float* u       = (const float*)d_in[0];
  const float* W_in    = (const float*)d_in[1];
  const float* conv_w  = (const float*)d_in[2];
  const float* conv_b  = (const float*)d_in[3];
  const float* dt_bias = (const float*)d_in[4];
  const float* A_log   = (const float*)d_in[5];
  const float* Dv      = (const float*)d_in[6];
  const float* norm_w  = (const float*)d_in[7];
  const float* W_out   = (const float*)d_in[8];

  float* out  = (float*)d_out;
  float* zout = out + (size_t)BL * DMODEL;

  char* ws = (char*)d_ws;
  size_t off = 0;
  auto alloc = [&](size_t bytes){ size_t o = off; off += (bytes + 255) & ~(size_t)255; return o; };
  size_t o_ubf    = alloc((size_t)N_U * 2);
  size_t o_wbf    = alloc((size_t)N_WIN * 2);
  size_t o_woutbf = alloc((size_t)N_WOUT * 2);
  size_t o_xbcdt  = alloc((size_t)BL * XWIDTH * 4);    // f32; later reused as ybf
  size_t o_xconv  = alloc((size_t)BL * CONVDIM * 2);   // bf16
  size_t o_dt     = alloc((size_t)BL * NHEADS * 4);
  size_t o_acum   = alloc((size_t)1024 * 256 * 4);
  size_t o_decay  = alloc((size_t)1024 * 4);
  size_t o_states = alloc((size_t)1024 * 512 * 4);
  size_t o_prev   = alloc((size_t)1024 * 512 * 4);
  size_t o_ynbf   = alloc((size_t)BL * DINNER * 2);

  unsigned short* ubf    = (unsigned short*)(ws + o_ubf);
  unsigned short* wbf    = (unsigned short*)(ws + o_wbf);
  unsigned short* woutbf = (unsigned short*)(ws + o_woutbf);
  float*          xbcdt  = (float*)(ws + o_xbcdt);
  unsigned short* xconv  = (unsigned short*)(ws + o_xconv);
  float*          dtws   = (float*)(ws + o_dt);
  float*          acum   = (float*)(ws + o_acum);
  float*          decay  = (float*)(ws + o_decay);
  float*          states = (float*)(ws + o_states);
  float*          prevb  = (float*)(ws + o_prev);
  unsigned short* ynbf   = (unsigned short*)(ws + o_ynbf);
  unsigned short* ybf    = (unsigned short*)(ws + o_xbcdt);  // reuse xbcdt region

  cast_all<<<(N_U + N_WIN + N_WOUT) / 256, 256, 0, stream>>>(u, W_in, W_out, ubf, wbf, woutbf);

  gemm_bf16<0><<<dim3(NPAD / 128, BL / 128), 256, 0, stream>>>(ubf, wbf, DMODEL, zout, xbcdt, 0);

  conv_dt_kernel<<<(BL * XW4 + 255) / 256, 256, 0, stream>>>(xbcdt, conv_w, conv_b, dt_bias, xconv, dtws);

  ssd_phaseA<<<dim3(16, 64), 256, 0, stream>>>(xconv, dtws, A_log, acum, decay, states);
  ssd_phaseB<<<128, 512, 0, stream>>>(states, decay, prevb);
  ssd_phaseC_mfma<<<dim3(16, 64), 256, 0, stream>>>(xconv, dtws, acum, prevb, Dv, ybf);

  gate_norm<<<BL, 256, 0, stream>>>(ybf, zout, norm_w, ynbf);

  gemm_bf16<1><<<dim3(DMODEL / 128, BL / 128), 256, 0, stream>>>(ynbf, woutbf, DINNER, out, nullptr, DMODEL);
}

// Round 13
// 212.881 us; speedup vs baseline: 1.1985x; 1.1088x over previous
//
#include <hip/hip_runtime.h>

#define BATCH   2
#define SEQLEN  2048
#define DMODEL  1024
#define DINNER  2048
#define NHEADS  64
#define HEADDIM 32
#define DSTATE  16
#define CONVDIM 2080
#define DINPROJ 4192
#define NPAD    4224
#define CHUNK   256
#define NCHUNK  8
#define BL      (BATCH*SEQLEN)   // 4096
#define XWIDTH  2144             // CONVDIM + NHEADS
#define XW4     (XWIDTH/4)       // 536

#define N_U     (BL*DMODEL)      // 4194304
#define N_WIN   (NPAD*DMODEL)    // 4325376
#define N_WOUT  (DMODEL*DINNER)  // 2097152

typedef float          f4    __attribute__((ext_vector_type(4)));
typedef short          s16x8 __attribute__((ext_vector_type(8)));
typedef unsigned short u16x4 __attribute__((ext_vector_type(4)));
typedef __bf16         bf16x8 __attribute__((ext_vector_type(8)));
typedef float          f32x4v __attribute__((ext_vector_type(4)));

#define MFMA16(a,b,c) __builtin_amdgcn_mfma_f32_16x16x32_bf16((a),(b),(c),0,0,0)

__device__ __forceinline__ unsigned short f2bf(float f){
  unsigned int u = __float_as_uint(f);
  u += 0x7FFFu + ((u >> 16) & 1u);
  return (unsigned short)(u >> 16);
}
__device__ __forceinline__ float bf2f(unsigned short u){
  return __uint_as_float(((unsigned int)u) << 16);
}
__device__ __forceinline__ __bf16 bitbf(unsigned short u){
  return __builtin_bit_cast(__bf16, u);
}

__device__ __forceinline__ void gload_lds16(const void* g, void* l){
  __builtin_amdgcn_global_load_lds((const __attribute__((address_space(1))) unsigned int*)g,
                                   (__attribute__((address_space(3))) unsigned int*)l,
                                   16, 0, 0);
}

__device__ __forceinline__ bf16x8 f32x8_to_frag(const float* src, bool valid){
  bf16x8 r;
  if (valid) {
    f4 a = *(const f4*)src;
    f4 c = *(const f4*)(src + 4);
    r[0]=(__bf16)a[0]; r[1]=(__bf16)a[1]; r[2]=(__bf16)a[2]; r[3]=(__bf16)a[3];
    r[4]=(__bf16)c[0]; r[5]=(__bf16)c[1]; r[6]=(__bf16)c[2]; r[7]=(__bf16)c[3];
  } else {
    r[0]=(__bf16)0.f; r[1]=(__bf16)0.f; r[2]=(__bf16)0.f; r[3]=(__bf16)0.f;
    r[4]=(__bf16)0.f; r[5]=(__bf16)0.f; r[6]=(__bf16)0.f; r[7]=(__bf16)0.f;
  }
  return r;
}

__device__ __forceinline__ bf16x8 bf16x8_load(const unsigned short* src, bool valid){
  if (valid) {
    s16x8 v = *(const s16x8*)src;
    return *(bf16x8*)&v;
  }
  bf16x8 r;
  r[0]=(__bf16)0.f; r[1]=(__bf16)0.f; r[2]=(__bf16)0.f; r[3]=(__bf16)0.f;
  r[4]=(__bf16)0.f; r[5]=(__bf16)0.f; r[6]=(__bf16)0.f; r[7]=(__bf16)0.f;
  return r;
}

// ---------------- fused casts: u, W_in (padded), W_out -> bf16 ----------------
__global__ void cast_all(const float* __restrict__ u, const float* __restrict__ W_in,
                         const float* __restrict__ W_out,
                         unsigned short* __restrict__ ubf, unsigned short* __restrict__ wbf,
                         unsigned short* __restrict__ woutbf){
  int i = blockIdx.x * 256 + threadIdx.x;
  if (i < N_U) {
    ubf[i] = f2bf(u[i]);
  } else if (i < N_U + N_WIN) {
    int j = i - N_U;
    int r = j >> 10;
    wbf[j] = (r < DINPROJ) ? f2bf(W_in[j]) : (unsigned short)0;
  } else {
    int j = i - N_U - N_WIN;
    woutbf[j] = f2bf(W_out[j]);
  }
}

// ---------------- bf16 MFMA GEMM 128x128, proven R6 structure ----------------
template<int MODE>
__global__ __launch_bounds__(256) void gemm_bf16(
    const unsigned short* __restrict__ A,
    const unsigned short* __restrict__ B,
    int K, float* __restrict__ C0, float* __restrict__ C1, int N)
{
  __shared__ unsigned short As[2][128][32];
  __shared__ unsigned short Bs[2][128][32];

  const int nx   = gridDim.x;
  const int flat = blockIdx.y * nx + blockIdx.x;
  const int q    = (nx * gridDim.y) >> 3;
  const int swz  = (flat & 7) * q + (flat >> 3);
  const int bm   = swz / nx, bn = swz % nx;

  const int tid  = threadIdx.x;
  const int wave = tid >> 6, lane = tid & 63;
  const int wm   = (wave >> 1) * 64, wn = (wave & 1) * 64;
  const int lrow = lane & 15, khalf = lane >> 4;
  const int cread = (khalf ^ ((lrow >> 1) & 3)) * 8;

  const int srow = wave * 16 + (lane >> 2);
  const int scol = ((lane & 3) ^ ((lane >> 3) & 3)) * 8;
  const unsigned short* Ag = A + (size_t)(bm * 128 + srow) * K + scol;
  const unsigned short* Bg = B + (size_t)(bn * 128 + srow) * K + scol;
  const int lr0 = wave * 16;

  f32x4v acc[4][4];
  #pragma unroll
  for (int i = 0; i < 4; ++i)
    #pragma unroll
    for (int j = 0; j < 4; ++j)
      acc[i][j] = (f32x4v){0.f,0.f,0.f,0.f};

  auto stage = [&](int buf, int k0){
    gload_lds16(Ag + k0,                   &As[buf][lr0][0]);
    gload_lds16(Ag + k0 + (size_t)64 * K,  &As[buf][64 + lr0][0]);
    gload_lds16(Bg + k0,                   &Bs[buf][lr0][0]);
    gload_lds16(Bg + k0 + (size_t)64 * K,  &Bs[buf][64 + lr0][0]);
  };

  const int NT = K >> 5;
  stage(0, 0);
  stage(1, 32);
  for (int t = 0; t < NT; ++t) {
    const int cur = t & 1;
    if (t + 1 < NT) { asm volatile("s_waitcnt vmcnt(4)" ::: "memory"); }
    else            { asm volatile("s_waitcnt vmcnt(0)" ::: "memory"); }
    __builtin_amdgcn_s_barrier();
    __builtin_amdgcn_sched_barrier(0);
    bf16x8 af[4], bfr[4];
    #pragma unroll
    for (int i = 0; i < 4; ++i) {
      af[i]  = *(const bf16x8*)&As[cur][wm + i * 16 + lrow][cread];
      bfr[i] = *(const bf16x8*)&Bs[cur][wn + i * 16 + lrow][cread];
    }
    __builtin_amdgcn_s_setprio(1);
    #pragma unroll
    for (int mi = 0; mi < 4; ++mi)
      #pragma unroll
      for (int ni = 0; ni < 4; ++ni)
        acc[mi][ni] = MFMA16(af[mi], bfr[ni], acc[mi][ni]);
    __builtin_amdgcn_s_setprio(0);
    __builtin_amdgcn_s_barrier();
    __builtin_amdgcn_sched_barrier(0);
    if (t + 2 < NT) stage(cur, (t + 2) << 5);
  }

  const int orow0 = bm * 128 + wm;
  const int ocol0 = bn * 128 + wn;
  #pragma unroll
  for (int mi = 0; mi < 4; ++mi)
    #pragma unroll
    for (int ni = 0; ni < 4; ++ni) {
      int col  = ocol0 + ni * 16 + lrow;
      int rowb = orow0 + mi * 16 + khalf * 4;
      #pragma unroll
      for (int r = 0; r < 4; ++r) {
        int row = rowb + r;
        float v = acc[mi][ni][r];
        if (MODE == 0) {
          if (col < DINNER)        C0[(size_t)row * DINNER + col] = v;
          else if (col < DINPROJ)  C1[(size_t)row * XWIDTH + (col - DINNER)] = v;
        } else {
          C0[(size_t)row * N + col] = v;
        }
      }
    }
}

// ---------------- conv1d + dt, x4-channel vectorized ----------------
__global__ __launch_bounds__(256) void conv_dt_kernel(
    const float* __restrict__ xbcdt,
    const float* __restrict__ conv_w, const float* __restrict__ conv_b,
    const float* __restrict__ dt_bias,
    unsigned short* __restrict__ xconv, float* __restrict__ dtout)
{
  int idx = blockIdx.x * 256 + threadIdx.x;     // BL * 536 total
  if (idx >= BL * XW4) return;
  int c4 = idx % XW4;
  int bl = idx / XW4;
  int l  = bl & (SEQLEN - 1);
  int ch = c4 * 4;
  if (ch < CONVDIM) {
    f4 acc = *(const f4*)&conv_b[ch];
    #pragma unroll
    for (int j = 0; j < 4; ++j) {
      int ls = l - 3 + j;
      f4 x = (ls >= 0) ? *(const f4*)&xbcdt[(size_t)(bl - 3 + j) * XWIDTH + ch]
                       : (f4){0.f,0.f,0.f,0.f};
      #pragma unroll
      for (int k = 0; k < 4; ++k) acc[k] += conv_w[(ch + k) * 4 + j] * x[k];
    }
    u16x4 o;
    #pragma unroll
    for (int k = 0; k < 4; ++k) {
      float s = acc[k] / (1.f + __expf(-acc[k]));
      o[k] = f2bf(s);
    }
    *(u16x4*)&xconv[(size_t)bl * CONVDIM + ch] = o;
  } else {
    int h = ch - CONVDIM;
    f4 x = *(const f4*)&xbcdt[(size_t)bl * XWIDTH + ch];
    f4 bz = *(const f4*)&dt_bias[h];
    f4 o;
    #pragma unroll
    for (int k = 0; k < 4; ++k) {
      float v = x[k] + bz[k];
      o[k] = (v > 20.f) ? v : log1pf(__expf(v));
    }
    *(f4*)&dtout[(size_t)bl * NHEADS + h] = o;
  }
}

// ---------------- SSD phase A: Acum scan + chunk states (MFMA einsum) ----------------
// states[p][n] = sum_l (coef[l]*X[l][p]) * B[l][n]  == 32x16x256 matmul via MFMA.
__global__ __launch_bounds__(256) void ssd_phaseA(
    const unsigned short* __restrict__ xconv, const float* __restrict__ dt,
    const float* __restrict__ A_log,
    float* __restrict__ acum, float* __restrict__ decay, float* __restrict__ states)
{
  int bc = blockIdx.x, h = blockIdx.y;
  int b = bc >> 3;
  int t = threadIdx.x;
  const int wave = t >> 6, lane = t & 63;
  const int l16 = lane & 15, khalf = lane >> 4;
  __shared__ float sAc[256], sCoef[256], sDt[256];
  __shared__ __bf16 sXT[32][264];   // [p][l] = X[l][p] (coef applied post-scan)
  __shared__ __bf16 sBT[16][264];   // [n][l] = B[l][n]
  __shared__ float sRed[4][2][16][16];
  int rowbase = b * SEQLEN + (bc & 7) * CHUNK;
  float dtv = dt[(rowbase + t) * NHEADS + h];
  float Av  = -__expf(A_log[h]);
  sAc[t] = dtv * Av; sDt[t] = dtv;

  // stage X^T (phaseC's verified transpose pattern)
  {
    int l  = t >> 3;
    int p0 = (t & 7) * 4;
    #pragma unroll
    for (int pass = 0; pass < 8; ++pass) {
      int ls = l + pass * 32;
      u16x4 v = *(const u16x4*)(xconv + (size_t)(rowbase + ls) * CONVDIM + h * 32 + p0);
      #pragma unroll
      for (int j = 0; j < 4; ++j) sXT[p0 + j][ls] = bitbf(v[j]);
    }
  }
  // stage B^T: thread t owns row l=t (16 bf16)
  {
    const unsigned short* br = xconv + (size_t)(rowbase + t) * CONVDIM + DINNER;
    u16x4 b0 = *(const u16x4*)br;
    u16x4 b1 = *(const u16x4*)(br + 4);
    u16x4 b2 = *(const u16x4*)(br + 8);
    u16x4 b3 = *(const u16x4*)(br + 12);
    #pragma unroll
    for (int j = 0; j < 4; ++j) {
      sBT[j][t]      = bitbf(b0[j]);
      sBT[4 + j][t]  = bitbf(b1[j]);
      sBT[8 + j][t]  = bitbf(b2[j]);
      sBT[12 + j][t] = bitbf(b3[j]);
    }
  }
  __syncthreads();

  // inclusive scan of sAc over 256
  for (int off = 1; off < 256; off <<= 1) {
    float add = (t >= off) ? sAc[t - off] : 0.f;
    __syncthreads();
    sAc[t] += add;
    __syncthreads();
  }
  int bch = bc * 64 + h;
  acum[(size_t)bch * 256 + t] = sAc[t];
  float last = sAc[255];
  if (t == 0) decay[bch] = __expf(last);
  sCoef[t] = sDt[t] * __expf(last - sAc[t]);
  __syncthreads();

  // apply coef to column t of sXT
  {
    float c = sCoef[t];
    #pragma unroll
    for (int p = 0; p < 32; ++p) {
      unsigned short uv = __builtin_bit_cast(unsigned short, sXT[p][t]);
      sXT[p][t] = (__bf16)(bf2f(uv) * c);
    }
  }
  __syncthreads();

  // MFMA: wave handles K range [wave*64, wave*64+64)
  f32x4v a0 = (f32x4v){0.f,0.f,0.f,0.f};
  f32x4v a1 = (f32x4v){0.f,0.f,0.f,0.f};
  #pragma unroll
  for (int ks = 0; ks < 2; ++ks) {
    int kb = wave * 64 + ks * 32 + khalf * 8;
    bf16x8 bf = *(const bf16x8*)&sBT[l16][kb];
    bf16x8 x0 = *(const bf16x8*)&sXT[l16][kb];
    bf16x8 x1 = *(const bf16x8*)&sXT[16 + l16][kb];
    a0 = MFMA16(x0, bf, a0);
    a1 = MFMA16(x1, bf, a1);
  }
  #pragma unroll
  for (int r = 0; r < 4; ++r) {
    sRed[wave][0][khalf * 4 + r][l16] = a0[r];
    sRed[wave][1][khalf * 4 + r][l16] = a1[r];
  }
  __syncthreads();

  // reduce 4 wave-partials; states layout [p*16+n]
  #pragma unroll
  for (int o = 0; o < 2; ++o) {
    int oi = t + o * 256;
    int p = oi >> 4, n = oi & 15;
    float s = sRed[0][p >> 4][p & 15][n] + sRed[1][p >> 4][p & 15][n]
            + sRed[2][p >> 4][p & 15][n] + sRed[3][p >> 4][p & 15][n];
    states[(size_t)bch * 512 + oi] = s;
  }
}

// ---------------- SSD phase B: sequential chunk scan ----------------
__global__ void ssd_phaseB(const float* __restrict__ states, const float* __restrict__ decay,
                           float* __restrict__ prev)
{
  int bh = blockIdx.x;
  int b = bh >> 6, h = bh & 63;
  int t = threadIdx.x;           // 512
  float carry = 0.f;
  for (int c = 0; c < NCHUNK; ++c) {
    int bch = (b * 8 + c) * 64 + h;
    size_t base = (size_t)bch * 512 + t;
    prev[base] = carry;
    carry = decay[bch] * carry + states[base];
  }
}

// ---------------- SSD phase C (MFMA), y output bf16 ----------------
__global__ __launch_bounds__(256, 2) void ssd_phaseC_mfma(
    const unsigned short* __restrict__ xconv, const float* __restrict__ dt,
    const float* __restrict__ acum, const float* __restrict__ prev,
    const float* __restrict__ Dvec, unsigned short* __restrict__ ybf)
{
  const int bc = blockIdx.x, h = blockIdx.y;
  const int b = bc >> 3;
  const int rowbase = b * SEQLEN + (bc & 7) * CHUNK;
  const int bch = bc * 64 + h;
  const int tid = threadIdx.x, wave = tid >> 6, lane = tid & 63;
  const int l16 = lane & 15, khalf = lane >> 4;

  __shared__ float sAcum[256];
  __shared__ __bf16 sXT[32][264];
  __shared__ __bf16 sP[4][2][16][40];

  if (tid < 256) sAcum[tid] = acum[(size_t)bch * 256 + tid];
  {
    int l  = tid >> 3;
    int p0 = (tid & 7) * 4;
    #pragma unroll
    for (int pass = 0; pass < 8; ++pass) {
      int ls = l + pass * 32;
      const unsigned short* xr = xconv + (size_t)(rowbase + ls) * CONVDIM + h * 32 + p0;
      u16x4 v = *(const u16x4*)xr;
      float dtl = dt[(rowbase + ls) * NHEADS + h];
      #pragma unroll
      for (int j = 0; j < 4; ++j) sXT[p0 + j][ls] = (__bf16)(bf2f(v[j]) * dtl);
    }
  }

  const bool kv = (khalf < 2);
  bf16x8 bfr[16], cfr[4], pvf[2];
  #pragma unroll
  for (int i = 0; i < 16; ++i)
    bfr[i] = bf16x8_load(xconv + (size_t)(rowbase + i * 16 + l16) * CONVDIM + DINNER + khalf * 8, kv);
  #pragma unroll
  for (int t = 0; t < 4; ++t)
    cfr[t] = bf16x8_load(xconv + (size_t)(rowbase + (wave + 4 * t) * 16 + l16) * CONVDIM + DINNER + DSTATE + khalf * 8, kv);
  #pragma unroll
  for (int pt = 0; pt < 2; ++pt)
    pvf[pt] = f32x8_to_frag(prev + (size_t)bch * 512 + (pt * 16 + l16) * 16 + khalf * 8, kv);
  __syncthreads();

  const float Dh = Dvec[h];
  #pragma unroll
  for (int t = 0; t < 4; ++t) {
    const int LT = wave + 4 * t;
    const int lbase = LT * 16;
    float al[4], el[4];
    #pragma unroll
    for (int r = 0; r < 4; ++r) { al[r] = sAcum[lbase + khalf * 4 + r]; el[r] = __expf(al[r]); }
    f32x4v y0 = MFMA16(cfr[t], pvf[0], ((f32x4v){0.f,0.f,0.f,0.f}));
    f32x4v y1 = MFMA16(cfr[t], pvf[1], ((f32x4v){0.f,0.f,0.f,0.f}));
    #pragma unroll
    for (int r = 0; r < 4; ++r) { y0[r] *= el[r]; y1[r] *= el[r]; }

    #pragma unroll
    for (int kp = 0; kp < 8; ++kp) {
      if (2 * kp <= LT) {
        f32x4v s0 = MFMA16(cfr[t], bfr[2 * kp],     ((f32x4v){0.f,0.f,0.f,0.f}));
        f32x4v s1 = MFMA16(cfr[t], bfr[2 * kp + 1], ((f32x4v){0.f,0.f,0.f,0.f}));
        const int buf = kp & 1;
        #pragma unroll
        for (int r = 0; r < 4; ++r) {
          int l  = lbase + khalf * 4 + r;
          int sA = 2 * kp * 16 + l16;
          int sB2 = sA + 16;
          float p0 = (sA  <= l) ? s0[r] * __expf(al[r] - sAcum[sA])  : 0.f;
          float p1 = (sB2 <= l) ? s1[r] * __expf(al[r] - sAcum[sB2]) : 0.f;
          sP[wave][buf][khalf * 4 + r][l16]      = (__bf16)p0;
          sP[wave][buf][khalf * 4 + r][16 + l16] = (__bf16)p1;
        }
        bf16x8 pa  = *(const bf16x8*)&sP[wave][buf][l16][khalf * 8];
        bf16x8 xf0 = *(const bf16x8*)&sXT[l16][kp * 32 + khalf * 8];
        bf16x8 xf1 = *(const bf16x8*)&sXT[16 + l16][kp * 32 + khalf * 8];
        y0 = MFMA16(pa, xf0, y0);
        y1 = MFMA16(pa, xf1, y1);
      }
    }

    #pragma unroll
    for (int r = 0; r < 4; ++r) {
      int lg = rowbase + lbase + khalf * 4 + r;
      const unsigned short* xr = xconv + (size_t)lg * CONVDIM + h * 32;
      unsigned short* yr = ybf + (size_t)lg * DINNER + h * 32;
      yr[l16]      = f2bf(y0[r] + Dh * bf2f(xr[l16]));
      yr[16 + l16] = f2bf(y1[r] + Dh * bf2f(xr[16 + l16]));
    }
  }
}

// ---------------- gate (silu(z)) + RMSNorm -> bf16 (y input bf16) ----------------
__global__ __launch_bounds__(256) void gate_norm(const unsigned short* __restrict__ ybf,
    const float* __restrict__ z, const float* __restrict__ norm_w,
    unsigned short* __restrict__ ynbf)
{
  int row = blockIdx.x, t = threadIdx.x;
  const unsigned short* yr = ybf + (size_t)row * DINNER + t * 8;
  const float* zr = z + (size_t)row * DINNER + t * 8;
  s16x8 yv = *(const s16x8*)yr;
  f4 z0 = *(const f4*)zr;
  f4 z1 = *(const f4*)(zr + 4);
  float vals[8];
  float ss = 0.f;
  #pragma unroll
  for (int k = 0; k < 8; ++k) {
    float zv = (k < 4) ? z0[k] : z1[k - 4];
    float g  = zv / (1.f + __expf(-zv));
    float v  = bf2f((unsigned short)yv[k]) * g;
    vals[k] = v; ss += v * v;
  }
  #pragma unroll
  for (int o = 1; o < 64; o <<= 1) ss += __shfl_xor(ss, o);
  __shared__ float sred[4];
  if ((t & 63) == 0) sred[t >> 6] = ss;
  __syncthreads();
  float tot = sred[0] + sred[1] + sred[2] + sred[3];
  float scale = rsqrtf(tot * (1.f / DINNER) + 1e-5f);
  const float* nw = norm_w + t * 8;
  s16x8 o;
  #pragma unroll
  for (int k = 0; k < 8; ++k) o[k] = (short)f2bf(vals[k] * scale * nw[k]);
  *(s16x8*)&ynbf[(size_t)row * DINNER + t * 8] = o;
}

// ---------------- launch ----------------
extern "C" void kernel_launch(void* const* d_in, const int* in_sizes, int n_in,
                              void* d_out, int out_size, void* d_ws, size_t ws_size,
                              hipStream_t stream)
{
  const float* u       = (const float*)d_in[0];
  const float* W_in    = (const float*)d_in[1];
  const float* conv_w  = (const float*)d_in[2];
  const float* conv_b  = (const float*)d_in[3];
  const float* dt_bias = (const float*)d_in[4];
  const float* A_log   = (const float*)d_in[5];
  const float* Dv      = (const float*)d_in[6];
  const float* norm_w  = (const float*)d_in[7];
  const float* W_out   = (const float*)d_in[8];

  float* out  = (float*)d_out;
  float* zout = out + (size_t)BL * DMODEL;

  char* ws = (char*)d_ws;
  size_t off = 0;
  auto alloc = [&](size_t bytes){ size_t o = off; off += (bytes + 255) & ~(size_t)255; return o; };
  size_t o_ubf    = alloc((size_t)N_U * 2);
  size_t o_wbf    = alloc((size_t)N_WIN * 2);
  size_t o_woutbf = alloc((size_t)N_WOUT * 2);
  size_t o_xbcdt  = alloc((size_t)BL * XWIDTH * 4);    // f32; later reused as ybf
  size_t o_xconv  = alloc((size_t)BL * CONVDIM * 2);   // bf16
  size_t o_dt     = alloc((size_t)BL * NHEADS * 4);
  size_t o_acum   = alloc((size_t)1024 * 256 * 4);
  size_t o_decay  = alloc((size_t)1024 * 4);
  size_t o_states = alloc((size_t)1024 * 512 * 4);
  size_t o_prev   = alloc((size_t)1024 * 512 * 4);
  size_t o_ynbf   = alloc((size_t)BL * DINNER * 2);

  unsigned short* ubf    = (unsigned short*)(ws + o_ubf);
  unsigned short* wbf    = (unsigned short*)(ws + o_wbf);
  unsigned short* woutbf = (unsigned short*)(ws + o_woutbf);
  float*          xbcdt  = (float*)(ws + o_xbcdt);
  unsigned short* xconv  = (unsigned short*)(ws + o_xconv);
  float*          dtws   = (float*)(ws + o_dt);
  float*          acum   = (float*)(ws + o_acum);
  float*          decay  = (float*)(ws + o_decay);
  float*          states = (float*)(ws + o_states);
  float*          prevb  = (float*)(ws + o_prev);
  unsigned short* ynbf   = (unsigned short*)(ws + o_ynbf);
  unsigned short* ybf    = (unsigned short*)(ws + o_xbcdt);  // reuse xbcdt region

  cast_all<<<(N_U + N_WIN + N_WOUT) / 256, 256, 0, stream>>>(u, W_in, W_out, ubf, wbf, woutbf);

  gemm_bf16<0><<<dim3(NPAD / 128, BL / 128), 256, 0, stream>>>(ubf, wbf, DMODEL, zout, xbcdt, 0);

  conv_dt_kernel<<<(BL * XW4 + 255) / 256, 256, 0, stream>>>(xbcdt, conv_w, conv_b, dt_bias, xconv, dtws);

  ssd_phaseA<<<dim3(16, 64), 256, 0, stream>>>(xconv, dtws, A_log, acum, decay, states);
  ssd_phaseB<<<128, 512, 0, stream>>>(states, decay, prevb);
  ssd_phaseC_mfma<<<dim3(16, 64), 256, 0, stream>>>(xconv, dtws, acum, prevb, Dv, ybf);

  gate_norm<<<BL, 256, 0, stream>>>(ybf, zout, norm_w, ynbf);

  gemm_bf16<1><<<dim3(DMODEL / 128, BL / 128), 256, 0, stream>>>(ynbf, woutbf, DINNER, out, nullptr, DMODEL);
}

// Round 14
// 208.174 us; speedup vs baseline: 1.2256x; 1.0226x over previous
//
#include <hip/hip_runtime.h>

#define BATCH   2
#define SEQLEN  2048
#define DMODEL  1024
#define DINNER  2048
#define NHEADS  64
#define HEADDIM 32
#define DSTATE  16
#define CONVDIM 2080
#define DINPROJ 4192
#define NPAD    4224
#define CHUNK   256
#define NCHUNK  8
#define BL      (BATCH*SEQLEN)   // 4096
#define XWIDTH  2144             // CONVDIM + NHEADS
#define XW4     (XWIDTH/4)       // 536

#define N_U     (BL*DMODEL)      // 4194304
#define N_WIN   (NPAD*DMODEL)    // 4325376
#define N_WOUT  (DMODEL*DINNER)  // 2097152

typedef float          f4    __attribute__((ext_vector_type(4)));
typedef short          s16x8 __attribute__((ext_vector_type(8)));
typedef unsigned short u16x4 __attribute__((ext_vector_type(4)));
typedef __bf16         bf16x8 __attribute__((ext_vector_type(8)));
typedef float          f32x4v __attribute__((ext_vector_type(4)));

#define MFMA16(a,b,c) __builtin_amdgcn_mfma_f32_16x16x32_bf16((a),(b),(c),0,0,0)

__device__ __forceinline__ unsigned short f2bf(float f){
  unsigned int u = __float_as_uint(f);
  u += 0x7FFFu + ((u >> 16) & 1u);
  return (unsigned short)(u >> 16);
}
__device__ __forceinline__ float bf2f(unsigned short u){
  return __uint_as_float(((unsigned int)u) << 16);
}
__device__ __forceinline__ __bf16 bitbf(unsigned short u){
  return __builtin_bit_cast(__bf16, u);
}

__device__ __forceinline__ void gload_lds16(const void* g, void* l){
  __builtin_amdgcn_global_load_lds((const __attribute__((address_space(1))) unsigned int*)g,
                                   (__attribute__((address_space(3))) unsigned int*)l,
                                   16, 0, 0);
}

__device__ __forceinline__ bf16x8 f32x8_to_frag(const float* src, bool valid){
  bf16x8 r;
  if (valid) {
    f4 a = *(const f4*)src;
    f4 c = *(const f4*)(src + 4);
    r[0]=(__bf16)a[0]; r[1]=(__bf16)a[1]; r[2]=(__bf16)a[2]; r[3]=(__bf16)a[3];
    r[4]=(__bf16)c[0]; r[5]=(__bf16)c[1]; r[6]=(__bf16)c[2]; r[7]=(__bf16)c[3];
  } else {
    r[0]=(__bf16)0.f; r[1]=(__bf16)0.f; r[2]=(__bf16)0.f; r[3]=(__bf16)0.f;
    r[4]=(__bf16)0.f; r[5]=(__bf16)0.f; r[6]=(__bf16)0.f; r[7]=(__bf16)0.f;
  }
  return r;
}

__device__ __forceinline__ bf16x8 bf16x8_load(const unsigned short* src, bool valid){
  if (valid) {
    s16x8 v = *(const s16x8*)src;
    return *(bf16x8*)&v;
  }
  bf16x8 r;
  r[0]=(__bf16)0.f; r[1]=(__bf16)0.f; r[2]=(__bf16)0.f; r[3]=(__bf16)0.f;
  r[4]=(__bf16)0.f; r[5]=(__bf16)0.f; r[6]=(__bf16)0.f; r[7]=(__bf16)0.f;
  return r;
}

// ---------------- fused casts: u, W_in (padded), W_out -> bf16 ----------------
__global__ void cast_all(const float* __restrict__ u, const float* __restrict__ W_in,
                         const float* __restrict__ W_out,
                         unsigned short* __restrict__ ubf, unsigned short* __restrict__ wbf,
                         unsigned short* __restrict__ woutbf){
  int i = blockIdx.x * 256 + threadIdx.x;
  if (i < N_U) {
    ubf[i] = f2bf(u[i]);
  } else if (i < N_U + N_WIN) {
    int j = i - N_U;
    int r = j >> 10;
    wbf[j] = (r < DINPROJ) ? f2bf(W_in[j]) : (unsigned short)0;
  } else {
    int j = i - N_U - N_WIN;
    woutbf[j] = f2bf(W_out[j]);
  }
}

// ---------------- bf16 MFMA GEMM 128x128 (in_proj), proven R6 structure ----------------
template<int MODE>
__global__ __launch_bounds__(256) void gemm_bf16(
    const unsigned short* __restrict__ A,
    const unsigned short* __restrict__ B,
    int K, float* __restrict__ C0, float* __restrict__ C1, int N)
{
  __shared__ unsigned short As[2][128][32];
  __shared__ unsigned short Bs[2][128][32];

  const int nx   = gridDim.x;
  const int flat = blockIdx.y * nx + blockIdx.x;
  const int q    = (nx * gridDim.y) >> 3;
  const int swz  = (flat & 7) * q + (flat >> 3);
  const int bm   = swz / nx, bn = swz % nx;

  const int tid  = threadIdx.x;
  const int wave = tid >> 6, lane = tid & 63;
  const int wm   = (wave >> 1) * 64, wn = (wave & 1) * 64;
  const int lrow = lane & 15, khalf = lane >> 4;
  const int cread = (khalf ^ ((lrow >> 1) & 3)) * 8;

  const int srow = wave * 16 + (lane >> 2);
  const int scol = ((lane & 3) ^ ((lane >> 3) & 3)) * 8;
  const unsigned short* Ag = A + (size_t)(bm * 128 + srow) * K + scol;
  const unsigned short* Bg = B + (size_t)(bn * 128 + srow) * K + scol;
  const int lr0 = wave * 16;

  f32x4v acc[4][4];
  #pragma unroll
  for (int i = 0; i < 4; ++i)
    #pragma unroll
    for (int j = 0; j < 4; ++j)
      acc[i][j] = (f32x4v){0.f,0.f,0.f,0.f};

  auto stage = [&](int buf, int k0){
    gload_lds16(Ag + k0,                   &As[buf][lr0][0]);
    gload_lds16(Ag + k0 + (size_t)64 * K,  &As[buf][64 + lr0][0]);
    gload_lds16(Bg + k0,                   &Bs[buf][lr0][0]);
    gload_lds16(Bg + k0 + (size_t)64 * K,  &Bs[buf][64 + lr0][0]);
  };

  const int NT = K >> 5;
  stage(0, 0);
  stage(1, 32);
  for (int t = 0; t < NT; ++t) {
    const int cur = t & 1;
    if (t + 1 < NT) { asm volatile("s_waitcnt vmcnt(4)" ::: "memory"); }
    else            { asm volatile("s_waitcnt vmcnt(0)" ::: "memory"); }
    __builtin_amdgcn_s_barrier();
    __builtin_amdgcn_sched_barrier(0);
    bf16x8 af[4], bfr[4];
    #pragma unroll
    for (int i = 0; i < 4; ++i) {
      af[i]  = *(const bf16x8*)&As[cur][wm + i * 16 + lrow][cread];
      bfr[i] = *(const bf16x8*)&Bs[cur][wn + i * 16 + lrow][cread];
    }
    __builtin_amdgcn_s_setprio(1);
    #pragma unroll
    for (int mi = 0; mi < 4; ++mi)
      #pragma unroll
      for (int ni = 0; ni < 4; ++ni)
        acc[mi][ni] = MFMA16(af[mi], bfr[ni], acc[mi][ni]);
    __builtin_amdgcn_s_setprio(0);
    __builtin_amdgcn_s_barrier();
    __builtin_amdgcn_sched_barrier(0);
    if (t + 2 < NT) stage(cur, (t + 2) << 5);
  }

  const int orow0 = bm * 128 + wm;
  const int ocol0 = bn * 128 + wn;
  #pragma unroll
  for (int mi = 0; mi < 4; ++mi)
    #pragma unroll
    for (int ni = 0; ni < 4; ++ni) {
      int col  = ocol0 + ni * 16 + lrow;
      int rowb = orow0 + mi * 16 + khalf * 4;
      #pragma unroll
      for (int r = 0; r < 4; ++r) {
        int row = rowb + r;
        float v = acc[mi][ni][r];
        if (MODE == 0) {
          if (col < DINNER)        C0[(size_t)row * DINNER + col] = v;
          else if (col < DINPROJ)  C1[(size_t)row * XWIDTH + (col - DINNER)] = v;
        } else {
          C0[(size_t)row * N + col] = v;
        }
      }
    }
}

// ------- out_proj split-K: grid (8, 32, 2); z = K-half; identical inner structure -------
// Each block: 128x128 tile, K_len=1024 at stride 2048. Partials to Cp[z].
__global__ __launch_bounds__(256) void gemm_out_splitk(
    const unsigned short* __restrict__ A,   // [4096][2048] bf16
    const unsigned short* __restrict__ B,   // [1024][2048] bf16
    float* __restrict__ Cp)                 // [2][4096][1024] partials
{
  __shared__ unsigned short As[2][128][32];
  __shared__ unsigned short Bs[2][128][32];
  const int Kst = DINNER;        // stride
  const int KL  = DINNER / 2;    // 1024 per half

  const int nx   = gridDim.x;    // 8
  const int flat = blockIdx.y * nx + blockIdx.x;
  const int q    = (nx * gridDim.y) >> 3;
  const int swz  = (flat & 7) * q + (flat >> 3);
  const int bm   = swz / nx, bn = swz % nx;
  const int kz   = blockIdx.z;

  const int tid  = threadIdx.x;
  const int wave = tid >> 6, lane = tid & 63;
  const int wm   = (wave >> 1) * 64, wn = (wave & 1) * 64;
  const int lrow = lane & 15, khalf = lane >> 4;
  const int cread = (khalf ^ ((lrow >> 1) & 3)) * 8;

  const int srow = wave * 16 + (lane >> 2);
  const int scol = ((lane & 3) ^ ((lane >> 3) & 3)) * 8;
  const unsigned short* Ag = A + (size_t)(bm * 128 + srow) * Kst + kz * KL + scol;
  const unsigned short* Bg = B + (size_t)(bn * 128 + srow) * Kst + kz * KL + scol;
  const int lr0 = wave * 16;

  f32x4v acc[4][4];
  #pragma unroll
  for (int i = 0; i < 4; ++i)
    #pragma unroll
    for (int j = 0; j < 4; ++j)
      acc[i][j] = (f32x4v){0.f,0.f,0.f,0.f};

  auto stage = [&](int buf, int k0){
    gload_lds16(Ag + k0,                     &As[buf][lr0][0]);
    gload_lds16(Ag + k0 + (size_t)64 * Kst,  &As[buf][64 + lr0][0]);
    gload_lds16(Bg + k0,                     &Bs[buf][lr0][0]);
    gload_lds16(Bg + k0 + (size_t)64 * Kst,  &Bs[buf][64 + lr0][0]);
  };

  const int NT = KL >> 5;   // 32
  stage(0, 0);
  stage(1, 32);
  for (int t = 0; t < NT; ++t) {
    const int cur = t & 1;
    if (t + 1 < NT) { asm volatile("s_waitcnt vmcnt(4)" ::: "memory"); }
    else            { asm volatile("s_waitcnt vmcnt(0)" ::: "memory"); }
    __builtin_amdgcn_s_barrier();
    __builtin_amdgcn_sched_barrier(0);
    bf16x8 af[4], bfr[4];
    #pragma unroll
    for (int i = 0; i < 4; ++i) {
      af[i]  = *(const bf16x8*)&As[cur][wm + i * 16 + lrow][cread];
      bfr[i] = *(const bf16x8*)&Bs[cur][wn + i * 16 + lrow][cread];
    }
    __builtin_amdgcn_s_setprio(1);
    #pragma unroll
    for (int mi = 0; mi < 4; ++mi)
      #pragma unroll
      for (int ni = 0; ni < 4; ++ni)
        acc[mi][ni] = MFMA16(af[mi], bfr[ni], acc[mi][ni]);
    __builtin_amdgcn_s_setprio(0);
    __builtin_amdgcn_s_barrier();
    __builtin_amdgcn_sched_barrier(0);
    if (t + 2 < NT) stage(cur, (t + 2) << 5);
  }

  float* C0 = Cp + (size_t)kz * BL * DMODEL;
  const int orow0 = bm * 128 + wm;
  const int ocol0 = bn * 128 + wn;
  #pragma unroll
  for (int mi = 0; mi < 4; ++mi)
    #pragma unroll
    for (int ni = 0; ni < 4; ++ni) {
      int col  = ocol0 + ni * 16 + lrow;
      int rowb = orow0 + mi * 16 + khalf * 4;
      #pragma unroll
      for (int r = 0; r < 4; ++r)
        C0[(size_t)(rowb + r) * DMODEL + col] = acc[mi][ni][r];
    }
}

// ---------------- reduce split-K partials: out = P0 + P1 ----------------
__global__ __launch_bounds__(256) void reduce_out(const float* __restrict__ Cp,
                                                  float* __restrict__ out){
  int i = blockIdx.x * 256 + threadIdx.x;   // over BL*DMODEL/4
  const f4* p0 = (const f4*)Cp;
  const f4* p1 = (const f4*)(Cp + (size_t)BL * DMODEL);
  f4 a = p0[i], b = p1[i];
  ((f4*)out)[i] = (f4){a[0]+b[0], a[1]+b[1], a[2]+b[2], a[3]+b[3]};
}

// ---------------- conv1d + dt, x4-channel vectorized ----------------
__global__ __launch_bounds__(256) void conv_dt_kernel(
    const float* __restrict__ xbcdt,
    const float* __restrict__ conv_w, const float* __restrict__ conv_b,
    const float* __restrict__ dt_bias,
    unsigned short* __restrict__ xconv, float* __restrict__ dtout)
{
  int idx = blockIdx.x * 256 + threadIdx.x;     // BL * 536 total
  if (idx >= BL * XW4) return;
  int c4 = idx % XW4;
  int bl = idx / XW4;
  int l  = bl & (SEQLEN - 1);
  int ch = c4 * 4;
  if (ch < CONVDIM) {
    f4 acc = *(const f4*)&conv_b[ch];
    #pragma unroll
    for (int j = 0; j < 4; ++j) {
      int ls = l - 3 + j;
      f4 x = (ls >= 0) ? *(const f4*)&xbcdt[(size_t)(bl - 3 + j) * XWIDTH + ch]
                       : (f4){0.f,0.f,0.f,0.f};
      #pragma unroll
      for (int k = 0; k < 4; ++k) acc[k] += conv_w[(ch + k) * 4 + j] * x[k];
    }
    u16x4 o;
    #pragma unroll
    for (int k = 0; k < 4; ++k) {
      float s = acc[k] / (1.f + __expf(-acc[k]));
      o[k] = f2bf(s);
    }
    *(u16x4*)&xconv[(size_t)bl * CONVDIM + ch] = o;
  } else {
    int h = ch - CONVDIM;
    f4 x = *(const f4*)&xbcdt[(size_t)bl * XWIDTH + ch];
    f4 bz = *(const f4*)&dt_bias[h];
    f4 o;
    #pragma unroll
    for (int k = 0; k < 4; ++k) {
      float v = x[k] + bz[k];
      o[k] = (v > 20.f) ? v : log1pf(__expf(v));
    }
    *(f4*)&dtout[(size_t)bl * NHEADS + h] = o;
  }
}

// ---------------- SSD phase A: Acum scan + chunk states (MFMA einsum) ----------------
__global__ __launch_bounds__(256) void ssd_phaseA(
    const unsigned short* __restrict__ xconv, const float* __restrict__ dt,
    const float* __restrict__ A_log,
    float* __restrict__ acum, float* __restrict__ decay, float* __restrict__ states)
{
  int bc = blockIdx.x, h = blockIdx.y;
  int b = bc >> 3;
  int t = threadIdx.x;
  const int wave = t >> 6, lane = t & 63;
  const int l16 = lane & 15, khalf = lane >> 4;
  __shared__ float sAc[256], sCoef[256], sDt[256];
  __shared__ __bf16 sXT[32][264];   // [p][l] = X[l][p] (coef applied post-scan)
  __shared__ __bf16 sBT[16][264];   // [n][l] = B[l][n]
  __shared__ float sRed[4][2][16][16];
  int rowbase = b * SEQLEN + (bc & 7) * CHUNK;
  float dtv = dt[(rowbase + t) * NHEADS + h];
  float Av  = -__expf(A_log[h]);
  sAc[t] = dtv * Av; sDt[t] = dtv;

  {
    int l  = t >> 3;
    int p0 = (t & 7) * 4;
    #pragma unroll
    for (int pass = 0; pass < 8; ++pass) {
      int ls = l + pass * 32;
      u16x4 v = *(const u16x4*)(xconv + (size_t)(rowbase + ls) * CONVDIM + h * 32 + p0);
      #pragma unroll
      for (int j = 0; j < 4; ++j) sXT[p0 + j][ls] = bitbf(v[j]);
    }
  }
  {
    const unsigned short* br = xconv + (size_t)(rowbase + t) * CONVDIM + DINNER;
    u16x4 b0 = *(const u16x4*)br;
    u16x4 b1 = *(const u16x4*)(br + 4);
    u16x4 b2 = *(const u16x4*)(br + 8);
    u16x4 b3 = *(const u16x4*)(br + 12);
    #pragma unroll
    for (int j = 0; j < 4; ++j) {
      sBT[j][t]      = bitbf(b0[j]);
      sBT[4 + j][t]  = bitbf(b1[j]);
      sBT[8 + j][t]  = bitbf(b2[j]);
      sBT[12 + j][t] = bitbf(b3[j]);
    }
  }
  __syncthreads();

  for (int off = 1; off < 256; off <<= 1) {
    float add = (t >= off) ? sAc[t - off] : 0.f;
    __syncthreads();
    sAc[t] += add;
    __syncthreads();
  }
  int bch = bc * 64 + h;
  acum[(size_t)bch * 256 + t] = sAc[t];
  float last = sAc[255];
  if (t == 0) decay[bch] = __expf(last);
  sCoef[t] = sDt[t] * __expf(last - sAc[t]);
  __syncthreads();

  {
    float c = sCoef[t];
    #pragma unroll
    for (int p = 0; p < 32; ++p) {
      unsigned short uv = __builtin_bit_cast(unsigned short, sXT[p][t]);
      sXT[p][t] = (__bf16)(bf2f(uv) * c);
    }
  }
  __syncthreads();

  f32x4v a0 = (f32x4v){0.f,0.f,0.f,0.f};
  f32x4v a1 = (f32x4v){0.f,0.f,0.f,0.f};
  #pragma unroll
  for (int ks = 0; ks < 2; ++ks) {
    int kb = wave * 64 + ks * 32 + khalf * 8;
    bf16x8 bf = *(const bf16x8*)&sBT[l16][kb];
    bf16x8 x0 = *(const bf16x8*)&sXT[l16][kb];
    bf16x8 x1 = *(const bf16x8*)&sXT[16 + l16][kb];
    a0 = MFMA16(x0, bf, a0);
    a1 = MFMA16(x1, bf, a1);
  }
  #pragma unroll
  for (int r = 0; r < 4; ++r) {
    sRed[wave][0][khalf * 4 + r][l16] = a0[r];
    sRed[wave][1][khalf * 4 + r][l16] = a1[r];
  }
  __syncthreads();

  #pragma unroll
  for (int o = 0; o < 2; ++o) {
    int oi = t + o * 256;
    int p = oi >> 4, n = oi & 15;
    float s = sRed[0][p >> 4][p & 15][n] + sRed[1][p >> 4][p & 15][n]
            + sRed[2][p >> 4][p & 15][n] + sRed[3][p >> 4][p & 15][n];
    states[(size_t)bch * 512 + oi] = s;
  }
}

// ---------------- SSD phase B: sequential chunk scan ----------------
__global__ void ssd_phaseB(const float* __restrict__ states, const float* __restrict__ decay,
                           float* __restrict__ prev)
{
  int bh = blockIdx.x;
  int b = bh >> 6, h = bh & 63;
  int t = threadIdx.x;           // 512
  float carry = 0.f;
  for (int c = 0; c < NCHUNK; ++c) {
    int bch = (b * 8 + c) * 64 + h;
    size_t base = (size_t)bch * 512 + t;
    prev[base] = carry;
    carry = decay[bch] * carry + states[base];
  }
}

// ---------------- SSD phase C (MFMA), y output bf16 ----------------
__global__ __launch_bounds__(256, 2) void ssd_phaseC_mfma(
    const unsigned short* __restrict__ xconv, const float* __restrict__ dt,
    const float* __restrict__ acum, const float* __restrict__ prev,
    const float* __restrict__ Dvec, unsigned short* __restrict__ ybf)
{
  const int bc = blockIdx.x, h = blockIdx.y;
  const int b = bc >> 3;
  const int rowbase = b * SEQLEN + (bc & 7) * CHUNK;
  const int bch = bc * 64 + h;
  const int tid = threadIdx.x, wave = tid >> 6, lane = tid & 63;
  const int l16 = lane & 15, khalf = lane >> 4;

  __shared__ float sAcum[256];
  __shared__ __bf16 sXT[32][264];
  __shared__ __bf16 sP[4][2][16][40];

  if (tid < 256) sAcum[tid] = acum[(size_t)bch * 256 + tid];
  {
    int l  = tid >> 3;
    int p0 = (tid & 7) * 4;
    #pragma unroll
    for (int pass = 0; pass < 8; ++pass) {
      int ls = l + pass * 32;
      const unsigned short* xr = xconv + (size_t)(rowbase + ls) * CONVDIM + h * 32 + p0;
      u16x4 v = *(const u16x4*)xr;
      float dtl = dt[(rowbase + ls) * NHEADS + h];
      #pragma unroll
      for (int j = 0; j < 4; ++j) sXT[p0 + j][ls] = (__bf16)(bf2f(v[j]) * dtl);
    }
  }

  const bool kv = (khalf < 2);
  bf16x8 bfr[16], cfr[4], pvf[2];
  #pragma unroll
  for (int i = 0; i < 16; ++i)
    bfr[i] = bf16x8_load(xconv + (size_t)(rowbase + i * 16 + l16) * CONVDIM + DINNER + khalf * 8, kv);
  #pragma unroll
  for (int t = 0; t < 4; ++t)
    cfr[t] = bf16x8_load(xconv + (size_t)(rowbase + (wave + 4 * t) * 16 + l16) * CONVDIM + DINNER + DSTATE + khalf * 8, kv);
  #pragma unroll
  for (int pt = 0; pt < 2; ++pt)
    pvf[pt] = f32x8_to_frag(prev + (size_t)bch * 512 + (pt * 16 + l16) * 16 + khalf * 8, kv);
  __syncthreads();

  const float Dh = Dvec[h];
  #pragma unroll
  for (int t = 0; t < 4; ++t) {
    const int LT = wave + 4 * t;
    const int lbase = LT * 16;
    float al[4], el[4];
    #pragma unroll
    for (int r = 0; r < 4; ++r) { al[r] = sAcum[lbase + khalf * 4 + r]; el[r] = __expf(al[r]); }
    f32x4v y0 = MFMA16(cfr[t], pvf[0], ((f32x4v){0.f,0.f,0.f,0.f}));
    f32x4v y1 = MFMA16(cfr[t], pvf[1], ((f32x4v){0.f,0.f,0.f,0.f}));
    #pragma unroll
    for (int r = 0; r < 4; ++r) { y0[r] *= el[r]; y1[r] *= el[r]; }

    #pragma unroll
    for (int kp = 0; kp < 8; ++kp) {
      if (2 * kp <= LT) {
        f32x4v s0 = MFMA16(cfr[t], bfr[2 * kp],     ((f32x4v){0.f,0.f,0.f,0.f}));
        f32x4v s1 = MFMA16(cfr[t], bfr[2 * kp + 1], ((f32x4v){0.f,0.f,0.f,0.f}));
        const int buf = kp & 1;
        #pragma unroll
        for (int r = 0; r < 4; ++r) {
          int l  = lbase + khalf * 4 + r;
          int sA = 2 * kp * 16 + l16;
          int sB2 = sA + 16;
          float p0 = (sA  <= l) ? s0[r] * __expf(al[r] - sAcum[sA])  : 0.f;
          float p1 = (sB2 <= l) ? s1[r] * __expf(al[r] - sAcum[sB2]) : 0.f;
          sP[wave][buf][khalf * 4 + r][l16]      = (__bf16)p0;
          sP[wave][buf][khalf * 4 + r][16 + l16] = (__bf16)p1;
        }
        bf16x8 pa  = *(const bf16x8*)&sP[wave][buf][l16][khalf * 8];
        bf16x8 xf0 = *(const bf16x8*)&sXT[l16][kp * 32 + khalf * 8];
        bf16x8 xf1 = *(const bf16x8*)&sXT[16 + l16][kp * 32 + khalf * 8];
        y0 = MFMA16(pa, xf0, y0);
        y1 = MFMA16(pa, xf1, y1);
      }
    }

    #pragma unroll
    for (int r = 0; r < 4; ++r) {
      int lg = rowbase + lbase + khalf * 4 + r;
      const unsigned short* xr = xconv + (size_t)lg * CONVDIM + h * 32;
      unsigned short* yr = ybf + (size_t)lg * DINNER + h * 32;
      yr[l16]      = f2bf(y0[r] + Dh * bf2f(xr[l16]));
      yr[16 + l16] = f2bf(y1[r] + Dh * bf2f(xr[16 + l16]));
    }
  }
}

// ---------------- gate (silu(z)) + RMSNorm -> bf16 (y input bf16) ----------------
__global__ __launch_bounds__(256) void gate_norm(const unsigned short* __restrict__ ybf,
    const float* __restrict__ z, const float* __restrict__ norm_w,
    unsigned short* __restrict__ ynbf)
{
  int row = blockIdx.x, t = threadIdx.x;
  const unsigned short* yr = ybf + (size_t)row * DINNER + t * 8;
  const float* zr = z + (size_t)row * DINNER + t * 8;
  s16x8 yv = *(const s16x8*)yr;
  f4 z0 = *(const f4*)zr;
  f4 z1 = *(const f4*)(zr + 4);
  float vals[8];
  float ss = 0.f;
  #pragma unroll
  for (int k = 0; k < 8; ++k) {
    float zv = (k < 4) ? z0[k] : z1[k - 4];
    float g  = zv / (1.f + __expf(-zv));
    float v  = bf2f((unsigned short)yv[k]) * g;
    vals[k] = v; ss += v * v;
  }
  #pragma unroll
  for (int o = 1; o < 64; o <<= 1) ss += __shfl_xor(ss, o);
  __shared__ float sred[4];
  if ((t & 63) == 0) sred[t >> 6] = ss;
  __syncthreads();
  float tot = sred[0] + sred[1] + sred[2] + sred[3];
  float scale = rsqrtf(tot * (1.f / DINNER) + 1e-5f);
  const float* nw = norm_w + t * 8;
  s16x8 o;
  #pragma unroll
  for (int k = 0; k < 8; ++k) o[k] = (short)f2bf(vals[k] * scale * nw[k]);
  *(s16x8*)&ynbf[(size_t)row * DINNER + t * 8] = o;
}

// ---------------- launch ----------------
extern "C" void kernel_launch(void* const* d_in, const int* in_sizes, int n_in,
                              void* d_out, int out_size, void* d_ws, size_t ws_size,
                              hipStream_t stream)
{
  const float* u       = (const float*)d_in[0];
  const float* W_in    = (const float*)d_in[1];
  const float* conv_w  = (const float*)d_in[2];
  const float* conv_b  = (const float*)d_in[3];
  const float* dt_bias = (const float*)d_in[4];
  const float* A_log   = (const float*)d_in[5];
  const float* Dv      = (const float*)d_in[6];
  const float* norm_w  = (const float*)d_in[7];
  const float* W_out   = (const float*)d_in[8];

  float* out  = (float*)d_out;
  float* zout = out + (size_t)BL * DMODEL;

  char* ws = (char*)d_ws;
  size_t off = 0;
  auto alloc = [&](size_t bytes){ size_t o = off; off += (bytes + 255) & ~(size_t)255; return o; };
  size_t o_ubf    = alloc((size_t)N_U * 2);
  size_t o_wbf    = alloc((size_t)N_WIN * 2);
  size_t o_woutbf = alloc((size_t)N_WOUT * 2);
  size_t o_xbcdt  = alloc((size_t)BL * XWIDTH * 4);    // f32; reused as ybf, then split-K partials
  size_t o_xconv  = alloc((size_t)BL * CONVDIM * 2);   // bf16
  size_t o_dt     = alloc((size_t)BL * NHEADS * 4);
  size_t o_acum   = alloc((size_t)1024 * 256 * 4);
  size_t o_decay  = alloc((size_t)1024 * 4);
  size_t o_states = alloc((size_t)1024 * 512 * 4);
  size_t o_prev   = alloc((size_t)1024 * 512 * 4);
  size_t o_ynbf   = alloc((size_t)BL * DINNER * 2);

  unsigned short* ubf    = (unsigned short*)(ws + o_ubf);
  unsigned short* wbf    = (unsigned short*)(ws + o_wbf);
  unsigned short* woutbf = (unsigned short*)(ws + o_woutbf);
  float*          xbcdt  = (float*)(ws + o_xbcdt);
  unsigned short* xconv  = (unsigned short*)(ws + o_xconv);
  float*          dtws   = (float*)(ws + o_dt);
  float*          acum   = (float*)(ws + o_acum);
  float*          decay  = (float*)(ws + o_decay);
  float*          states = (float*)(ws + o_states);
  float*          prevb  = (float*)(ws + o_prev);
  unsigned short* ynbf   = (unsigned short*)(ws + o_ynbf);
  unsigned short* ybf    = (unsigned short*)(ws + o_xbcdt);  // reuse xbcdt region
  float*          cpart  = (float*)(ws + o_xbcdt);           // reuse again after gate_norm
                                                             // (2 * 16.78 MB <= 35.1 MB region)

  cast_all<<<(N_U + N_WIN + N_WOUT) / 256, 256, 0, stream>>>(u, W_in, W_out, ubf, wbf, woutbf);

  gemm_bf16<0><<<dim3(NPAD / 128, BL / 128), 256, 0, stream>>>(ubf, wbf, DMODEL, zout, xbcdt, 0);

  conv_dt_kernel<<<(BL * XW4 + 255) / 256, 256, 0, stream>>>(xbcdt, conv_w, conv_b, dt_bias, xconv, dtws);

  ssd_phaseA<<<dim3(16, 64), 256, 0, stream>>>(xconv, dtws, A_log, acum, decay, states);
  ssd_phaseB<<<128, 512, 0, stream>>>(states, decay, prevb);
  ssd_phaseC_mfma<<<dim3(16, 64), 256, 0, stream>>>(xconv, dtws, acum, prevb, Dv, ybf);

  gate_norm<<<BL, 256, 0, stream>>>(ybf, zout, norm_w, ynbf);

  gemm_out_splitk<<<dim3(DMODEL / 128, BL / 128, 2), 256, 0, stream>>>(ynbf, woutbf, cpart);
  reduce_out<<<(BL * DMODEL / 4) / 256, 256, 0, stream>>>(cpart, out);
}